// Round 9
// baseline (448.097 us; speedup 1.0000x reference)
//
#include <hip/hip_runtime.h>

typedef unsigned short u16;
typedef __attribute__((ext_vector_type(8))) short bf8_t;   // 8 x bf16 (4 VGPRs)
typedef __attribute__((ext_vector_type(4))) float f4_t;

#define MFMA_B16(a,b,c) __builtin_amdgcn_mfma_f32_16x16x32_bf16(a,b,c,0,0,0)

// ---------- problem constants ----------
#define TOKS 8192   // B*T = 4*2048
#define HS   1024
#define DKTOT 512
#define DVTOT 1024
#define IM   2816

// ---------- workspace layout (bytes) ----------
constexpr size_t OFF_WQT    = 0;
constexpr size_t OFF_WKT    = OFF_WQT    + (size_t)DKTOT*HS*2;        // contiguous: q,k,v,g one slab
constexpr size_t OFF_WVT    = OFF_WKT    + (size_t)DKTOT*HS*2;
constexpr size_t OFF_WGT    = OFF_WVT    + (size_t)DVTOT*HS*2;
constexpr size_t OFF_WOT    = OFF_WGT    + (size_t)DVTOT*HS*2;
constexpr size_t OFF_WGATET = OFF_WOT    + (size_t)HS*DVTOT*2;
constexpr size_t OFF_WUPT   = OFF_WGATET + (size_t)IM*HS*2;
constexpr size_t OFF_WDOWNT = OFF_WUPT   + (size_t)IM*HS*2;
constexpr size_t OFF_QE     = OFF_WDOWNT + (size_t)HS*IM*2;           // bf16 8 MiB
constexpr size_t OFF_CTST   = OFF_QE     + (size_t)TOKS*DKTOT*2;      // bf16 32 MiB (CT -> S in place)
constexpr size_t OFF_DEC    = OFF_CTST   + (size_t)512*256*128*2;     // fp32 256 KiB
constexpr size_t OFF_R1     = OFF_DEC    + (size_t)512*128*4;
constexpr size_t OFF_QKB    = OFF_R1;                                 // bf16 [8192][1024] 16 MiB
constexpr size_t OFF_GLOG   = OFF_QKB    + (size_t)TOKS*1024*2;       // fp32 16 MiB
constexpr size_t OFF_VT     = OFF_GLOG   + (size_t)TOKS*DKTOT*4;      // bf16 16 MiB
constexpr size_t OFF_UP     = OFF_R1;                                 // bf16 44 MiB (aliases QK/GLOG/VT)
constexpr size_t OFF_R3     = OFF_R1 + 50331648;
constexpr size_t OFF_H      = OFF_R3;                                 // bf16 16 MiB
constexpr size_t OFF_OI     = OFF_R3;                                 // (after H dead)
constexpr size_t OFF_N2     = OFF_R3;                                 // (after OI dead)
constexpr size_t OFF_R4     = OFF_R3 + 16777216;
constexpr size_t OFF_GO     = OFF_R4;                                 // bf16 16 MiB
constexpr size_t OFF_OG     = OFF_R4;                                 // in-place with GO
constexpr size_t WS_NEED    = OFF_R4 + 16777216;

// ---------- helpers ----------
__device__ __forceinline__ u16 f2bf(float f){
  union{ float f; unsigned u; } x; x.f = f;
  unsigned r = x.u + 0x7FFFu + ((x.u >> 16) & 1u);   // RNE
  return (u16)(r >> 16);
}
__device__ __forceinline__ float bf2f(u16 u){
  union{ unsigned u; float f; } x; x.u = ((unsigned)u) << 16; return x.f;
}
__device__ __forceinline__ void gl_lds16(const void* g, void* l){
  __builtin_amdgcn_global_load_lds(
      (const __attribute__((address_space(1))) unsigned int*)g,
      (__attribute__((address_space(3))) unsigned int*)l, 16, 0, 0);
}
// XOR-swizzled LDS byte addressing (writer+reader both use these => bijective, safe)
__device__ __forceinline__ int swz128(int row, int cb){ return row*128 + (cb ^ ((row & 7)  << 4)); }
__device__ __forceinline__ int swz256(int row, int cb){ return row*256 + (cb ^ ((row & 15) << 4)); }

// XCD-aware + L2-aware block mapping. Requires nwg % 8 == 0 (all grids here comply).
__device__ __forceinline__ void xcd_map(int gx, int gy, int& bm, int& bn){
  const int i   = blockIdx.y*gx + blockIdx.x;
  const int cpx = (gx*gy) >> 3;
  const int j   = (i & 7)*cpx + (i >> 3);
  const int k   = j / (gx*8);
  const int jl  = j - k*(gx*8);
  bn = jl >> 3;
  bm = k*8 + (jl & 7);
}

// ---------- batched weight transpose fp32 (K x N) -> bf16 (N x K) ----------
struct TransAll {
  const float* src[8];
  u16* dst[8];
  int K[8];
  int N[8];
  int end[8];   // cumulative tile counts
};

__global__ __launch_bounds__(256) void k_transpose_all(TransAll ta)
{
  __shared__ float tile[64][65];
  const int flat = blockIdx.x;
  int seg = 0, start = 0;
  #pragma unroll
  for(int j=0;j<8;j++){
    if(flat >= ta.end[j]){ seg = j+1; start = ta.end[j]; }
  }
  const float* W = ta.src[seg];
  u16* Wt = ta.dst[seg];
  const int K = ta.K[seg], N = ta.N[seg];
  const int local = flat - start;
  const int tilesX = N >> 6;
  const int n0 = (local % tilesX)*64, k0 = (local / tilesX)*64;
  const int tx = threadIdx.x & 63, tg = threadIdx.x >> 6;
  #pragma unroll
  for(int i=0;i<16;i++){
    int kr = tg*16 + i;
    tile[kr][tx] = W[(size_t)(k0+kr)*N + n0 + tx];
  }
  __syncthreads();
  #pragma unroll
  for(int i=0;i<16;i++){
    int nr = tg*16 + i;
    Wt[(size_t)(n0+nr)*K + k0 + tx] = f2bf(tile[tx][nr]);
  }
}

// ---------- RMSNorm: fp32 row -> bf16 row (MLP norm) ----------
__global__ __launch_bounds__(256) void k_rmsnorm(
    const float* __restrict__ X, const float* __restrict__ W, u16* __restrict__ H)
{
  __shared__ float red[4];
  const size_t row = blockIdx.x;
  const int t = threadIdx.x;
  const float4 v = ((const float4*)(X + row*1024))[t];
  float ss = v.x*v.x + v.y*v.y + v.z*v.z + v.w*v.w;
  #pragma unroll
  for(int m=32;m>=1;m>>=1) ss += __shfl_xor(ss, m, 64);
  if((t & 63) == 0) red[t >> 6] = ss;
  __syncthreads();
  ss = red[0] + red[1] + red[2] + red[3];
  const float rs = rsqrtf(ss*(1.f/1024.f) + 1e-6f);
  const float4 w = ((const float4*)W)[t];
  ushort4 o;
  o.x = f2bf(v.x*rs*w.x);
  o.y = f2bf(v.y*rs*w.y);
  o.z = f2bf(v.z*rs*w.z);
  o.w = f2bf(v.w*rs*w.w);
  ((ushort4*)H)[row*256 + t] = o;
}

// ---------- fused attention RMSNorm + low-rank gate logits ----------
__global__ __launch_bounds__(256) void k_rms_glog(
    const float* __restrict__ X, const float* __restrict__ W, u16* __restrict__ H,
    const float* __restrict__ W1, const float* __restrict__ W2,
    const float* __restrict__ bias, float* __restrict__ G)
{
  __shared__ float hs[1024];
  __shared__ float red2[16][17];
  __shared__ float rr[16];
  __shared__ float red[4];
  const size_t row = blockIdx.x;
  const int t = threadIdx.x;
  const float4 v = ((const float4*)(X + row*1024))[t];
  float ss = v.x*v.x + v.y*v.y + v.z*v.z + v.w*v.w;
  #pragma unroll
  for(int m=32;m>=1;m>>=1) ss += __shfl_xor(ss, m, 64);
  if((t & 63) == 0) red[t >> 6] = ss;
  __syncthreads();
  ss = red[0] + red[1] + red[2] + red[3];
  const float rs = rsqrtf(ss*(1.f/1024.f) + 1e-6f);
  const float4 w = ((const float4*)W)[t];
  const float h0 = v.x*rs*w.x, h1 = v.y*rs*w.y, h2 = v.z*rs*w.z, h3 = v.w*rs*w.w;
  ushort4 o; o.x = f2bf(h0); o.y = f2bf(h1); o.z = f2bf(h2); o.w = f2bf(h3);
  ((ushort4*)H)[row*256 + t] = o;
  hs[t*4+0] = h0; hs[t*4+1] = h1; hs[t*4+2] = h2; hs[t*4+3] = h3;
  __syncthreads();

  const int r = t & 15, c = t >> 4;
  float acc = 0.f;
  #pragma unroll
  for(int j=0;j<64;j++){
    int k = c*64 + ((j + c) & 63);
    acc += hs[k] * W1[(size_t)k*16 + r];
  }
  red2[c][r] = acc;
  __syncthreads();
  if(t < 16){
    float s2 = 0.f;
    #pragma unroll
    for(int cc=0;cc<16;cc++) s2 += red2[cc][t];
    rr[t] = s2;
  }
  __syncthreads();
  #pragma unroll
  for(int dd=0;dd<2;dd++){
    int dcol = t + dd*256;
    float z = bias[dcol];
    #pragma unroll
    for(int j=0;j<16;j++) z += rr[j]*W2[j*512 + dcol];
    float ls = fminf(z, 0.f) - log1pf(__expf(-fabsf(z)));
    G[row*512 + dcol] = ls * 0.0625f;
  }
}

enum { E_BF16=1, E_ADDF32=2, E_SILUMUL=3, E_QKVG=5 };

// ---------- pipelined GEMM (128x256, BK=64, 3-deep, vmcnt(6)) for N=1024 GEMMs --
template<int EPI>
__global__ __launch_bounds__(512, 2) void k_gemm8(
    const u16* __restrict__ A, const u16* __restrict__ Bt,
    void* __restrict__ Cp, const void* __restrict__ aux,
    int M, int N, int K)
{
  __shared__ __align__(16) u16 lds[3*24576];
  const int t = threadIdx.x;
  const int wv = t >> 6, ln = t & 63, lr = ln & 15, lg = ln >> 4;
  const int wm = wv >> 2, wn = wv & 3;
  int bm, bn; xcd_map(gridDim.x, gridDim.y, bm, bn);
  const int m0 = bm*128, n0 = bn*256;
  const int NT = K >> 6;

  const int sr = t >> 3;
  const int sc = ((t & 7)*16 ^ ((sr & 7) << 4)) >> 1;
  const u16* Asrc = A  + (size_t)(m0 + sr)*K + sc;
  const u16* Bsrc = Bt + (size_t)(n0 + sr)*K + sc;

  auto stage = [&](int T){
    const int b = T % 3;
    const size_t ko = (size_t)T * 64;
    u16* dA = lds + b*24576 + wv*512;
    u16* dB = lds + b*24576 + 8192 + wv*512;
    gl_lds16(Asrc + ko,                    dA);
    gl_lds16(Asrc + (size_t)64*K + ko,     dA + 4096);
    #pragma unroll
    for(int j=0;j<4;j++)
      gl_lds16(Bsrc + (size_t)(j*64)*K + ko, dB + j*4096);
  };

  f4_t acc[4][4];
  #pragma unroll
  for(int i=0;i<4;i++)
    #pragma unroll
    for(int j=0;j<4;j++) acc[i][j] = f4_t{0.f,0.f,0.f,0.f};

  const int rA = wm*64 + lr;
  const int rB = wn*64 + lr;
  const int cxor = (lr & 7) << 4;

  auto compute = [&](int b){
    const char* La = (const char*)(lds + b*24576);
    const char* Lb = La + 16384;
    #pragma unroll
    for(int kk=0;kk<2;++kk){
      const int cb = (kk*64 + lg*16) ^ cxor;
      bf8_t af[4], bfr[4];
      #pragma unroll
      for(int m=0;m<4;m++) af[m]  = *(const bf8_t*)(La + (rA + m*16)*128 + cb);
      #pragma unroll
      for(int n=0;n<4;n++) bfr[n] = *(const bf8_t*)(Lb + (rB + n*16)*128 + cb);
      __builtin_amdgcn_s_setprio(1);
      #pragma unroll
      for(int m=0;m<4;m++)
        #pragma unroll
        for(int n=0;n<4;n++)
          acc[m][n] = MFMA_B16(af[m], bfr[n], acc[m][n]);
      __builtin_amdgcn_s_setprio(0);
    }
  };

  stage(0);
  stage(1);

  for(int T=0; T<NT-1; ++T){
    asm volatile("s_waitcnt vmcnt(6)" ::: "memory");
    __builtin_amdgcn_s_barrier();
    asm volatile("" ::: "memory");
    __builtin_amdgcn_sched_barrier(0);
    if(T+2 < NT) stage(T+2);
    compute(T % 3);
  }
  asm volatile("s_waitcnt vmcnt(0)" ::: "memory");
  __builtin_amdgcn_s_barrier();
  asm volatile("" ::: "memory");
  __builtin_amdgcn_sched_barrier(0);
  compute((NT-1) % 3);

  #pragma unroll
  for(int m=0;m<4;m++){
    #pragma unroll
    for(int n=0;n<4;n++){
      const int row0 = m0 + wm*64 + m*16 + lg*4;
      const int col  = n0 + wn*64 + n*16 + lr;
      #pragma unroll
      for(int r=0;r<4;r++){
        const size_t idx = (size_t)(row0+r)*N + col;
        float v = acc[m][n][r];
        if constexpr(EPI==E_BF16) ((u16*)Cp)[idx] = f2bf(v);
        else if constexpr(EPI==E_ADDF32) ((float*)Cp)[idx] = v + ((const float*)aux)[idx];
        else if constexpr(EPI==E_SILUMUL){
          float u = bf2f(((const u16*)aux)[idx]);
          ((u16*)Cp)[idx] = f2bf(u * v / (1.f + __expf(-v)));
        }
      }
    }
  }
}

// ---------- 256x256 8-phase GEMM (m201-style), for N>=2816 GEMMs ----------
// 8 waves (2M x 4N), per-wave output 128x64, BK=64, 2 LDS buffers of 64KB.
// LDS per buffer: A at +0, B at +32768; each mat: [2 Kh][128 row-pairs][128B],
// swizzle: off = pg*128 + ((((R&1)<<6)|(lg<<4)) ^ ((pg&7)<<4))  -> 2-way banks.
// Phases per iter (2 K-tiles): split per-wave work by (kk, m-half); stage one
// 16KB unit (2 gl_lds16/thread) per phase; vmcnt(6) at phases 4,8 only.
template<int EPI>
__global__ __launch_bounds__(512, 2) void k_gemm10(
    const u16* __restrict__ A, const u16* __restrict__ Bt,
    void* __restrict__ Cp, const void* __restrict__ aux,
    int M, int N, int K)
{
  __shared__ __align__(16) char lds[131072];   // 128 KB
  const int t = threadIdx.x;
  const int wv = t >> 6, ln = t & 63, lr = ln & 15, lg = ln >> 4;
  const int wm = wv >> 2, wn = wv & 3;         // 2 M-waves x 4 N-waves
  int bm, bn; xcd_map(gridDim.x, gridDim.y, bm, bn);
  const int m0 = bm*256, n0 = bn*256;
  const int NT = K >> 6;                       // even for all users

  // per-thread staging geometry (derived + element-verified):
  // unit = 16KB (256 rows x 32 K-el); issue q covers rows rloc + q*128.
  const int sl   = t & 7;
  const int pgl  = (t >> 3) & 7;
  const int unsw = 16*(sl ^ pgl);
  const int rloc = ((t >> 3) << 1) + (unsw >> 6);
  const int cole = (unsw & 63) >> 1;
  const u16* Asrc = A  + (size_t)(m0 + rloc)*K + cole;
  const u16* Bsrc = Bt + (size_t)(n0 + rloc)*K + cole;

  auto STAGE = [&](int tt, int mat, int kh){
    if(tt >= NT) return;
    const size_t ko = (size_t)tt*64 + kh*32;
    const u16* s = mat ? Bsrc : Asrc;
    char* d = lds + ((tt & 1) << 16) + (mat << 15) + (kh << 14) + (wv << 10);
    gl_lds16(s + ko,                  d);
    gl_lds16(s + (size_t)128*K + ko,  d + 8192);
  };

  f4_t acc[8][4];
  #pragma unroll
  for(int i=0;i<8;i++)
    #pragma unroll
    for(int j=0;j<4;j++) acc[i][j] = f4_t{0.f,0.f,0.f,0.f};

  bf8_t bfr[4];
  auto LDB = [&](int buf, int kk){
    #pragma unroll
    for(int n=0;n<4;n++){
      const int R = wn*64 + n*16 + lr;
      const int pg = R >> 1;
      const int off = (buf<<16) + 32768 + (kk<<14) + pg*128
                    + ((((R&1)<<6) | (lg<<4)) ^ ((pg&7)<<4));
      bfr[n] = *(const bf8_t*)(lds + off);
    }
  };
  auto MFMAPH = [&](int buf, int kk, int mh){
    bf8_t af[4];
    #pragma unroll
    for(int m=0;m<4;m++){
      const int R = wm*128 + (mh*4+m)*16 + lr;
      const int pg = R >> 1;
      const int off = (buf<<16) + (kk<<14) + pg*128
                    + ((((R&1)<<6) | (lg<<4)) ^ ((pg&7)<<4));
      af[m] = *(const bf8_t*)(lds + off);
    }
    asm volatile("s_waitcnt lgkmcnt(0)" ::: "memory");
    __builtin_amdgcn_sched_barrier(0);
    __builtin_amdgcn_s_setprio(1);
    #pragma unroll
    for(int m=0;m<4;m++)
      #pragma unroll
      for(int n=0;n<4;n++)
        acc[mh*4+m][n] = MFMA_B16(af[m], bfr[n], acc[mh*4+m][n]);
    __builtin_amdgcn_s_setprio(0);
  };

  #define GBAR do{ asm volatile("" ::: "memory"); __builtin_amdgcn_s_barrier(); \
                   asm volatile("" ::: "memory"); }while(0)

  // prologue: tile0 fully + tile1's B0,A0,B1; vmcnt(6) keeps tile1's 3 units.
  STAGE(0,1,0); STAGE(0,0,0); STAGE(0,1,1); STAGE(0,0,1);
  STAGE(1,1,0); STAGE(1,0,0); STAGE(1,1,1);
  asm volatile("s_waitcnt vmcnt(6)" ::: "memory");
  GBAR;

  const int NI = NT >> 1;
  for(int j=0; j<NI; ++j){
    const int t1 = 2*j+1;
    const bool last = (j == NI-1);
    // ph1: buf0 (kk0, mh0); stage A-Kh1(t1) -> buf1
    LDB(0,0); STAGE(t1,0,1);          MFMAPH(0,0,0); GBAR;
    // ph2: buf0 (kk0, mh1); stage B-Kh0(t1+1) -> buf0
    STAGE(t1+1,1,0);                  MFMAPH(0,0,1); GBAR;
    // ph3: buf0 (kk1, mh0); stage A-Kh0(t1+1) -> buf0
    LDB(0,1); STAGE(t1+1,0,0);        MFMAPH(0,1,0); GBAR;
    // ph4: buf0 (kk1, mh1); stage B-Kh1(t1+1) -> buf0; vmcnt
    STAGE(t1+1,1,1);                  MFMAPH(0,1,1);
    if(last) asm volatile("s_waitcnt vmcnt(0)" ::: "memory");
    else     asm volatile("s_waitcnt vmcnt(6)" ::: "memory");
    GBAR;
    // ph5: buf1 (kk0, mh0); stage A-Kh1(t1+1) -> buf0
    LDB(1,0); STAGE(t1+1,0,1);        MFMAPH(1,0,0); GBAR;
    // ph6: buf1 (kk0, mh1); stage B-Kh0(t1+2) -> buf1
    STAGE(t1+2,1,0);                  MFMAPH(1,0,1); GBAR;
    // ph7: buf1 (kk1, mh0); stage A-Kh0(t1+2) -> buf1
    LDB(1,1); STAGE(t1+2,0,0);        MFMAPH(1,1,0); GBAR;
    // ph8: buf1 (kk1, mh1); stage B-Kh1(t1+2) -> buf1; vmcnt
    STAGE(t1+2,1,1);                  MFMAPH(1,1,1);
    if(!last){ asm volatile("s_waitcnt vmcnt(6)" ::: "memory"); }
    GBAR;
  }
  #undef GBAR

  #pragma unroll
  for(int m=0;m<8;m++){
    #pragma unroll
    for(int n=0;n<4;n++){
      const int row0 = m0 + wm*128 + m*16 + lg*4;
      const int col  = n0 + wn*64 + n*16 + lr;
      if constexpr(EPI==E_QKVG){
        char* wsb = (char*)Cp;
        if(n0 < 1024){                       // q,k -> qkb [8192][1024]
          u16* dst = (u16*)(wsb + OFF_QKB);
          #pragma unroll
          for(int r=0;r<4;r++) dst[(size_t)(row0+r)*1024 + col] = f2bf(acc[m][n][r]);
        } else if(n0 < 2048){                // v -> vtb transposed [1024][8192]
          u16* dst = (u16*)(wsb + OFF_VT);
          ushort4 u;
          u.x = f2bf(acc[m][n][0]); u.y = f2bf(acc[m][n][1]);
          u.z = f2bf(acc[m][n][2]); u.w = f2bf(acc[m][n][3]);
          *(ushort4*)(dst + (size_t)(col-1024)*TOKS + row0) = u;
        } else {                             // g -> gob [8192][1024]
          u16* dst = (u16*)(wsb + OFF_GO);
          #pragma unroll
          for(int r=0;r<4;r++) dst[(size_t)(row0+r)*1024 + (col-2048)] = f2bf(acc[m][n][r]);
        }
      } else {
        #pragma unroll
        for(int r=0;r<4;r++){
          const size_t idx = (size_t)(row0+r)*N + col;
          float v = acc[m][n][r];
          if constexpr(EPI==E_BF16) ((u16*)Cp)[idx] = f2bf(v);
          else if constexpr(EPI==E_ADDF32) ((float*)Cp)[idx] = v + ((const float*)aux)[idx];
          else if constexpr(EPI==E_SILUMUL){
            float u = bf2f(((const u16*)aux)[idx]);
            ((u16*)Cp)[idx] = f2bf(u * v / (1.f + __expf(-v)));
          }
        }
      }
    }
  }
}

// ---------- GLA phase A ----------
__global__ __launch_bounds__(256) void k_gla_a(
    const u16* __restrict__ QK,
    const u16* __restrict__ VT, const float* __restrict__ G,
    u16* __restrict__ QE, u16* __restrict__ OI,
    u16* __restrict__ CT, float* __restrict__ DEC)
{
  __shared__ __align__(16) u16 qe_s[64*128];
  __shared__ __align__(16) u16 ke_s[64*128];
  __shared__ __align__(16) u16 kd_s[128*64];
  __shared__ __align__(16) u16 a_s [64*64];
  __shared__ float ps_s[2][128];

  const int bid = blockIdx.x;
  const int nc = bid & 31, hh = (bid >> 5) & 3, bb = bid >> 7;
  const int bh = bb*4 + hh;
  const int tok0 = bb*2048 + nc*64;
  const int t = threadIdx.x;
  const size_t cbase = (size_t)(bh*32 + nc);

  {
    const int d = t & 127;
    const int half = t >> 7;
    const int col = hh*128 + d;
    const int i0 = half*32;
    float g[32];
    float psum = 0.f;
    #pragma unroll
    for(int i=0;i<32;i++){
      g[i] = G[(size_t)(tok0+i0+i)*512 + col];
      psum += g[i];
    }
    ps_s[half][d] = psum;
    __syncthreads();
    const float cum0  = half ? ps_s[0][d] : 0.f;
    const float blast = ps_s[0][d] + ps_s[1][d];
    if(half == 0) DEC[cbase*128 + d] = __expf(blast);
    float cum = cum0;
    #pragma unroll
    for(int i=0;i<32;i++){
      cum += g[i];
      const int tok = tok0 + i0 + i;
      float qv = bf2f(QK[(size_t)tok*1024 + col]);
      float kv = bf2f(QK[(size_t)tok*1024 + 512 + col]);
      float qe = qv * __expf(cum) * 0.08838834764831845f;
      float ke = kv * __expf(-cum);
      float kd = kv * __expf(blast - cum);
      *(u16*)((char*)qe_s + swz256(i0+i, d*2)) = f2bf(qe);
      *(u16*)((char*)ke_s + swz256(i0+i, d*2)) = f2bf(ke);
      *(u16*)((char*)kd_s + swz128(d, (i0+i)*2)) = f2bf(kd);
      QE[(cbase*64 + i0+i)*128 + d] = f2bf(qe);
    }
  }
  __syncthreads();

  const int wv = t >> 6, ln = t & 63, lr = ln & 15, lg = ln >> 4;

  bf8_t aq[4];
  #pragma unroll
  for(int ks=0;ks<4;ks++)
    aq[ks] = *(const bf8_t*)((const char*)qe_s + swz256(wv*16 + lr, ks*64 + lg*16));
  #pragma unroll
  for(int n=0;n<4;n++){
    f4_t accA = f4_t{0.f,0.f,0.f,0.f};
    #pragma unroll
    for(int ks=0;ks<4;ks++){
      bf8_t bk = *(const bf8_t*)((const char*)ke_s + swz256(n*16 + lr, ks*64 + lg*16));
      accA = MFMA_B16(aq[ks], bk, accA);
    }
    #pragma unroll
    for(int r=0;r<4;r++){
      int i = wv*16 + lg*4 + r;
      int s = n*16 + lr;
      float v = (s <= i) ? accA[r] : 0.f;
      *(u16*)((char*)a_s + swz128(i, s*2)) = f2bf(v);
    }
  }
  __syncthreads();

  bf8_t af[2], kf[2][2];
  #pragma unroll
  for(int ks=0;ks<2;ks++)
    af[ks] = *(const bf8_t*)((const char*)a_s + swz128(wv*16 + lr, ks*64 + lg*16));
  #pragma unroll
  for(int p=0;p<2;p++)
    #pragma unroll
    for(int ks=0;ks<2;ks++)
      kf[p][ks] = *(const bf8_t*)((const char*)kd_s + swz128((2*wv+p)*16 + lr, ks*64 + lg*16));

  #pragma unroll 4
  for(int ne=0; ne<16; ne++){
    bf8_t vf[2];
    #pragma unroll
    for(int ks=0;ks<2;ks++)
      vf[ks] = *(const bf8_t*)(VT + (size_t)(hh*256 + ne*16 + lr)*8192 + tok0 + ks*32 + lg*8);
    f4_t ao = f4_t{0.f,0.f,0.f,0.f};
    ao = MFMA_B16(af[0], vf[0], ao);
    ao = MFMA_B16(af[1], vf[1], ao);
    #pragma unroll
    for(int r=0;r<4;r++)
      OI[(cbase*64 + wv*16 + lg*4 + r)*256 + ne*16 + lr] = f2bf(ao[r]);
    f4_t c0 = f4_t{0.f,0.f,0.f,0.f}, c1 = f4_t{0.f,0.f,0.f,0.f};
    c0 = MFMA_B16(kf[0][0], vf[0], c0);
    c0 = MFMA_B16(kf[0][1], vf[1], c0);
    c1 = MFMA_B16(kf[1][0], vf[0], c1);
    c1 = MFMA_B16(kf[1][1], vf[1], c1);
    u16* dst = CT + (cbase*256 + ne*16 + lr)*128;
    ushort4 u0, u1;
    u0.x=f2bf(c0[0]); u0.y=f2bf(c0[1]); u0.z=f2bf(c0[2]); u0.w=f2bf(c0[3]);
    u1.x=f2bf(c1[0]); u1.y=f2bf(c1[1]); u1.z=f2bf(c1[2]); u1.w=f2bf(c1[3]);
    *(ushort4*)(dst + (2*wv+0)*16 + lg*4) = u0;
    *(ushort4*)(dst + (2*wv+1)*16 + lg*4) = u1;
  }
}

// ---------- GLA phase B ----------
__global__ __launch_bounds__(256) void k_scan(
    u16* __restrict__ CTST, const float* __restrict__ DEC)
{
  const int idx = blockIdx.x*256 + threadIdx.x;
  const int d = idx & 127;
  const int e = (idx >> 7) & 255;
  const int bh = idx >> 15;
  float s = 0.f;
  for(int n=0;n<32;n++){
    const size_t off = ((size_t)(bh*32 + n)*256 + e)*128 + d;
    float c = bf2f(CTST[off]);
    CTST[off] = f2bf(s);
    s = s * DEC[(bh*32+n)*128 + d] + c;
  }
}

// ---------- GLA phase C ----------
__global__ __launch_bounds__(256) void k_gla_c(
    const u16* __restrict__ QE, const u16* __restrict__ ST,
    const u16* __restrict__ OI, const u16* __restrict__ GO,
    const float* __restrict__ GW, u16* __restrict__ OG)
{
  const int bid = blockIdx.x;
  const int nc = bid & 31, hh = (bid >> 5) & 3, bb = bid >> 7;
  const int bh = bb*4 + hh;
  const int tok0 = bb*2048 + nc*64;
  const int t = threadIdx.x;
  const int wv = t >> 6, ln = t & 63, lr = ln & 15, lg = ln >> 4;
  const size_t cbase = (size_t)(bh*32 + nc);

  bf8_t qf[4];
  #pragma unroll
  for(int ks=0;ks<4;ks++)
    qf[ks] = *(const bf8_t*)(QE + (cbase*64 + wv*16 + lr)*128 + ks*32 + lg*8);

  f4_t acc[16];
  #pragma unroll
  for(int ne=0;ne<16;ne++){
    f4_t a = f4_t{0.f,0.f,0.f,0.f};
    #pragma unroll
    for(int ks=0;ks<4;ks++){
      bf8_t sf = *(const bf8_t*)(ST + (cbase*256 + ne*16 + lr)*128 + ks*32 + lg*8);
      a = MFMA_B16(qf[ks], sf, a);
    }
    acc[ne] = a;
  }

  float vals[16][4];
  float ss[4] = {0.f,0.f,0.f,0.f};
  #pragma unroll
  for(int ne=0;ne<16;ne++)
    #pragma unroll
    for(int r=0;r<4;r++){
      float v = acc[ne][r] + bf2f(OI[(cbase*64 + wv*16 + lg*4 + r)*256 + ne*16 + lr]);
      vals[ne][r] = v;
      ss[r] += v*v;
    }
  #pragma unroll
  for(int r=0;r<4;r++){
    ss[r] += __shfl_xor(ss[r], 1, 64);
    ss[r] += __shfl_xor(ss[r], 2, 64);
    ss[r] += __shfl_xor(ss[r], 4, 64);
    ss[r] += __shfl_xor(ss[r], 8, 64);
  }
  float rs[4];
  #pragma unroll
  for(int r=0;r<4;r++) rs[r] = rsqrtf(ss[r]*(1.f/256.f) + 1e-6f);

  #pragma unroll
  for(int ne=0;ne<16;ne++)
    #pragma unroll
    for(int r=0;r<4;r++){
      int i = wv*16 + lg*4 + r;
      int e = ne*16 + lr;
      const size_t idx = (size_t)(tok0+i)*1024 + hh*256 + e;
      float gg = bf2f(GO[idx]);
      float sg = gg / (1.f + __expf(-gg));
      OG[idx] = f2bf(vals[ne][r]*rs[r]*GW[e]*sg);
    }
}

extern "C" void kernel_launch(void* const* d_in, const int* in_sizes, int n_in,
                              void* d_out, int out_size, void* d_ws, size_t ws_size,
                              hipStream_t stream) {
  (void)in_sizes; (void)n_in; (void)out_size;
  if (ws_size < WS_NEED) return;

  const float* x       = (const float*)d_in[0];
  const float* attn_w  = (const float*)d_in[1];
  const float* Wq      = (const float*)d_in[2];
  const float* Wk      = (const float*)d_in[3];
  const float* Wv      = (const float*)d_in[4];
  const float* Wg      = (const float*)d_in[5];
  const float* Wgk1    = (const float*)d_in[6];
  const float* Wgk2    = (const float*)d_in[7];
  const float* bgk2    = (const float*)d_in[8];
  const float* gnw     = (const float*)d_in[9];
  const float* Wo      = (const float*)d_in[10];
  const float* mlpw    = (const float*)d_in[11];
  const float* Wgate   = (const float*)d_in[12];
  const float* Wup     = (const float*)d_in[13];
  const float* Wdown   = (const float*)d_in[14];
  char* ws = (char*)d_ws;

  u16*   wqt   = (u16*)(ws + OFF_WQT);
  u16*   wkt   = (u16*)(ws + OFF_WKT);
  u16*   wvt   = (u16*)(ws + OFF_WVT);
  u16*   wgt   = (u16*)(ws + OFF_WGT);
  u16*   wot   = (u16*)(ws + OFF_WOT);
  u16*   wgatet= (u16*)(ws + OFF_WGATET);
  u16*   wupt  = (u16*)(ws + OFF_WUPT);
  u16*   wdownt= (u16*)(ws + OFF_WDOWNT);
  u16*   qeb   = (u16*)(ws + OFF_QE);
  u16*   ctst  = (u16*)(ws + OFF_CTST);
  float* decb  = (float*)(ws + OFF_DEC);
  u16*   qkb   = (u16*)(ws + OFF_QKB);
  float* glogb = (float*)(ws + OFF_GLOG);
  u16*   vtb   = (u16*)(ws + OFF_VT);
  u16*   upb   = (u16*)(ws + OFF_UP);
  u16*   hb    = (u16*)(ws + OFF_H);
  u16*   oib   = (u16*)(ws + OFF_OI);
  u16*   n2b   = (u16*)(ws + OFF_N2);
  u16*   gob   = (u16*)(ws + OFF_GO);
  u16*   ogb   = (u16*)(ws + OFF_OG);
  float* x2b   = (float*)d_out;

  dim3 blk(256);
  dim3 blk8(512);

  TransAll ta;
  ta.src[0]=Wq;    ta.dst[0]=wqt;    ta.K[0]=HS;  ta.N[0]=DKTOT;
  ta.src[1]=Wk;    ta.dst[1]=wkt;    ta.K[1]=HS;  ta.N[1]=DKTOT;
  ta.src[2]=Wv;    ta.dst[2]=wvt;    ta.K[2]=HS;  ta.N[2]=DVTOT;
  ta.src[3]=Wg;    ta.dst[3]=wgt;    ta.K[3]=HS;  ta.N[3]=DVTOT;
  ta.src[4]=Wo;    ta.dst[4]=wot;    ta.K[4]=DVTOT; ta.N[4]=HS;
  ta.src[5]=Wgate; ta.dst[5]=wgatet; ta.K[5]=HS;  ta.N[5]=IM;
  ta.src[6]=Wup;   ta.dst[6]=wupt;   ta.K[6]=HS;  ta.N[6]=IM;
  ta.src[7]=Wdown; ta.dst[7]=wdownt; ta.K[7]=IM;  ta.N[7]=HS;
  {
    int cum = 0;
    for(int j=0;j<8;j++){ cum += (ta.N[j]>>6)*(ta.K[j]>>6); ta.end[j] = cum; }
  }
  k_transpose_all<<<3136, blk, 0, stream>>>(ta);

  // fused attention rmsnorm + gate logits, then one N=3072 GEMM for q|k|v|g
  k_rms_glog<<<TOKS, blk, 0, stream>>>(x, attn_w, hb, Wgk1, Wgk2, bgk2, glogb);
  k_gemm10<E_QKVG><<<dim3(12, 32), blk8, 0, stream>>>(hb, wqt, ws, nullptr, TOKS, 3072, HS);

  // GLA
  k_gla_a<<<512, blk, 0, stream>>>(qkb, vtb, glogb, qeb, oib, ctst, decb);
  k_scan <<<2048, blk, 0, stream>>>(ctst, decb);
  k_gla_c<<<512, blk, 0, stream>>>(qeb, ctst, oib, gob, gnw, ogb);

  // output projection + residual (x2 -> d_out as fp32)
  k_gemm8<E_ADDF32><<<dim3(4, 64), blk8, 0, stream>>>(ogb, wot, x2b, x, TOKS, HS, DVTOT);

  // MLP
  k_rmsnorm<<<TOKS, blk, 0, stream>>>(x2b, mlpw, n2b);
  k_gemm10<E_BF16>   <<<dim3(11, 32), blk8, 0, stream>>>(n2b, wupt,   upb, nullptr, TOKS, IM, HS);
  k_gemm10<E_SILUMUL><<<dim3(11, 32), blk8, 0, stream>>>(n2b, wgatet, upb, upb,     TOKS, IM, HS);
  k_gemm8<E_ADDF32>  <<<dim3(4, 64),  blk8, 0, stream>>>(upb, wdownt, x2b, x2b,     TOKS, HS, IM);
}

// Round 10
// 442.123 us; speedup vs baseline: 1.0135x; 1.0135x over previous
//
#include <hip/hip_runtime.h>

typedef unsigned short u16;
typedef __attribute__((ext_vector_type(8))) short bf8_t;   // 8 x bf16 (4 VGPRs)
typedef __attribute__((ext_vector_type(4))) float f4_t;

#define MFMA_B16(a,b,c) __builtin_amdgcn_mfma_f32_16x16x32_bf16(a,b,c,0,0,0)

// ---------- problem constants ----------
#define TOKS 8192   // B*T = 4*2048
#define HS   1024
#define DKTOT 512
#define DVTOT 1024
#define IM   2816

// ---------- workspace layout (bytes) ----------
constexpr size_t OFF_WQT    = 0;
constexpr size_t OFF_WKT    = OFF_WQT    + (size_t)DKTOT*HS*2;        // contiguous: q,k,v,g one slab
constexpr size_t OFF_WVT    = OFF_WKT    + (size_t)DKTOT*HS*2;
constexpr size_t OFF_WGT    = OFF_WVT    + (size_t)DVTOT*HS*2;
constexpr size_t OFF_WOT    = OFF_WGT    + (size_t)DVTOT*HS*2;
constexpr size_t OFF_WGATET = OFF_WOT    + (size_t)HS*DVTOT*2;
constexpr size_t OFF_WUPT   = OFF_WGATET + (size_t)IM*HS*2;
constexpr size_t OFF_WDOWNT = OFF_WUPT   + (size_t)IM*HS*2;
constexpr size_t OFF_QE     = OFF_WDOWNT + (size_t)HS*IM*2;           // bf16 8 MiB
constexpr size_t OFF_CTST   = OFF_QE     + (size_t)TOKS*DKTOT*2;      // bf16 32 MiB (CT -> S in place)
constexpr size_t OFF_DEC    = OFF_CTST   + (size_t)512*256*128*2;     // fp32 256 KiB
constexpr size_t OFF_R1     = OFF_DEC    + (size_t)512*128*4;
constexpr size_t OFF_QKB    = OFF_R1;                                 // bf16 [8192][1024] 16 MiB
constexpr size_t OFF_GLOG   = OFF_QKB    + (size_t)TOKS*1024*2;       // fp32 16 MiB
constexpr size_t OFF_VT     = OFF_GLOG   + (size_t)TOKS*DKTOT*4;      // bf16 16 MiB
constexpr size_t OFF_UP     = OFF_R1;                                 // bf16 44 MiB (aliases QK/GLOG/VT)
constexpr size_t OFF_R3     = OFF_R1 + 50331648;
constexpr size_t OFF_H      = OFF_R3;                                 // bf16 16 MiB
constexpr size_t OFF_OI     = OFF_R3;                                 // (after H dead)
constexpr size_t OFF_N2     = OFF_R3;                                 // (after OI dead)
constexpr size_t OFF_R4     = OFF_R3 + 16777216;
constexpr size_t OFF_GO     = OFF_R4;                                 // bf16 16 MiB
constexpr size_t OFF_OG     = OFF_R4;                                 // in-place with GO
constexpr size_t WS_NEED    = OFF_R4 + 16777216;

// ---------- helpers ----------
__device__ __forceinline__ u16 f2bf(float f){
  union{ float f; unsigned u; } x; x.f = f;
  unsigned r = x.u + 0x7FFFu + ((x.u >> 16) & 1u);   // RNE
  return (u16)(r >> 16);
}
__device__ __forceinline__ float bf2f(u16 u){
  union{ unsigned u; float f; } x; x.u = ((unsigned)u) << 16; return x.f;
}
__device__ __forceinline__ void gl_lds16(const void* g, void* l){
  __builtin_amdgcn_global_load_lds(
      (const __attribute__((address_space(1))) unsigned int*)g,
      (__attribute__((address_space(3))) unsigned int*)l, 16, 0, 0);
}
// XOR-swizzled LDS byte addressing (writer+reader both use these => bijective, safe)
__device__ __forceinline__ int swz128(int row, int cb){ return row*128 + (cb ^ ((row & 7)  << 4)); }
__device__ __forceinline__ int swz256(int row, int cb){ return row*256 + (cb ^ ((row & 15) << 4)); }

// XCD-aware + L2-aware block mapping. Requires nwg % 8 == 0 (all grids here comply).
__device__ __forceinline__ void xcd_map(int gx, int gy, int& bm, int& bn){
  const int i   = blockIdx.y*gx + blockIdx.x;
  const int cpx = (gx*gy) >> 3;
  const int j   = (i & 7)*cpx + (i >> 3);
  const int k   = j / (gx*8);
  const int jl  = j - k*(gx*8);
  bn = jl >> 3;
  bm = k*8 + (jl & 7);
}

// ---------- batched weight transpose fp32 (K x N) -> bf16 (N x K) ----------
struct TransAll {
  const float* src[8];
  u16* dst[8];
  int K[8];
  int N[8];
  int end[8];   // cumulative tile counts
};

__global__ __launch_bounds__(256) void k_transpose_all(TransAll ta)
{
  __shared__ float tile[64][65];
  const int flat = blockIdx.x;
  int seg = 0, start = 0;
  #pragma unroll
  for(int j=0;j<8;j++){
    if(flat >= ta.end[j]){ seg = j+1; start = ta.end[j]; }
  }
  const float* W = ta.src[seg];
  u16* Wt = ta.dst[seg];
  const int K = ta.K[seg], N = ta.N[seg];
  const int local = flat - start;
  const int tilesX = N >> 6;
  const int n0 = (local % tilesX)*64, k0 = (local / tilesX)*64;
  const int tx = threadIdx.x & 63, tg = threadIdx.x >> 6;
  #pragma unroll
  for(int i=0;i<16;i++){
    int kr = tg*16 + i;
    tile[kr][tx] = W[(size_t)(k0+kr)*N + n0 + tx];
  }
  __syncthreads();
  #pragma unroll
  for(int i=0;i<16;i++){
    int nr = tg*16 + i;
    Wt[(size_t)(n0+nr)*K + k0 + tx] = f2bf(tile[tx][nr]);
  }
}

// ---------- RMSNorm: fp32 row -> bf16 row (MLP norm) ----------
__global__ __launch_bounds__(256) void k_rmsnorm(
    const float* __restrict__ X, const float* __restrict__ W, u16* __restrict__ H)
{
  __shared__ float red[4];
  const size_t row = blockIdx.x;
  const int t = threadIdx.x;
  const float4 v = ((const float4*)(X + row*1024))[t];
  float ss = v.x*v.x + v.y*v.y + v.z*v.z + v.w*v.w;
  #pragma unroll
  for(int m=32;m>=1;m>>=1) ss += __shfl_xor(ss, m, 64);
  if((t & 63) == 0) red[t >> 6] = ss;
  __syncthreads();
  ss = red[0] + red[1] + red[2] + red[3];
  const float rs = rsqrtf(ss*(1.f/1024.f) + 1e-6f);
  const float4 w = ((const float4*)W)[t];
  ushort4 o;
  o.x = f2bf(v.x*rs*w.x);
  o.y = f2bf(v.y*rs*w.y);
  o.z = f2bf(v.z*rs*w.z);
  o.w = f2bf(v.w*rs*w.w);
  ((ushort4*)H)[row*256 + t] = o;
}

// ---------- fused attention RMSNorm + low-rank gate logits ----------
__global__ __launch_bounds__(256) void k_rms_glog(
    const float* __restrict__ X, const float* __restrict__ W, u16* __restrict__ H,
    const float* __restrict__ W1, const float* __restrict__ W2,
    const float* __restrict__ bias, float* __restrict__ G)
{
  __shared__ float hs[1024];
  __shared__ float red2[16][17];
  __shared__ float rr[16];
  __shared__ float red[4];
  const size_t row = blockIdx.x;
  const int t = threadIdx.x;
  const float4 v = ((const float4*)(X + row*1024))[t];
  float ss = v.x*v.x + v.y*v.y + v.z*v.z + v.w*v.w;
  #pragma unroll
  for(int m=32;m>=1;m>>=1) ss += __shfl_xor(ss, m, 64);
  if((t & 63) == 0) red[t >> 6] = ss;
  __syncthreads();
  ss = red[0] + red[1] + red[2] + red[3];
  const float rs = rsqrtf(ss*(1.f/1024.f) + 1e-6f);
  const float4 w = ((const float4*)W)[t];
  const float h0 = v.x*rs*w.x, h1 = v.y*rs*w.y, h2 = v.z*rs*w.z, h3 = v.w*rs*w.w;
  ushort4 o; o.x = f2bf(h0); o.y = f2bf(h1); o.z = f2bf(h2); o.w = f2bf(h3);
  ((ushort4*)H)[row*256 + t] = o;
  hs[t*4+0] = h0; hs[t*4+1] = h1; hs[t*4+2] = h2; hs[t*4+3] = h3;
  __syncthreads();

  const int r = t & 15, c = t >> 4;
  float acc = 0.f;
  #pragma unroll
  for(int j=0;j<64;j++){
    int k = c*64 + ((j + c) & 63);
    acc += hs[k] * W1[(size_t)k*16 + r];
  }
  red2[c][r] = acc;
  __syncthreads();
  if(t < 16){
    float s2 = 0.f;
    #pragma unroll
    for(int cc=0;cc<16;cc++) s2 += red2[cc][t];
    rr[t] = s2;
  }
  __syncthreads();
  #pragma unroll
  for(int dd=0;dd<2;dd++){
    int dcol = t + dd*256;
    float z = bias[dcol];
    #pragma unroll
    for(int j=0;j<16;j++) z += rr[j]*W2[j*512 + dcol];
    float ls = fminf(z, 0.f) - log1pf(__expf(-fabsf(z)));
    G[row*512 + dcol] = ls * 0.0625f;
  }
}

enum { E_BF16=1, E_ADDF32=2, E_SILUMUL=3, E_QKVG=5 };

// ---------- pipelined GEMM (128x256, BK=64, 3-deep, vmcnt(6)) for N=1024 GEMMs --
template<int EPI>
__global__ __launch_bounds__(512, 2) void k_gemm8(
    const u16* __restrict__ A, const u16* __restrict__ Bt,
    void* __restrict__ Cp, const void* __restrict__ aux,
    int M, int N, int K)
{
  __shared__ __align__(16) u16 lds[3*24576];
  const int t = threadIdx.x;
  const int wv = t >> 6, ln = t & 63, lr = ln & 15, lg = ln >> 4;
  const int wm = wv >> 2, wn = wv & 3;
  int bm, bn; xcd_map(gridDim.x, gridDim.y, bm, bn);
  const int m0 = bm*128, n0 = bn*256;
  const int NT = K >> 6;

  const int sr = t >> 3;
  const int sc = ((t & 7)*16 ^ ((sr & 7) << 4)) >> 1;
  const u16* Asrc = A  + (size_t)(m0 + sr)*K + sc;
  const u16* Bsrc = Bt + (size_t)(n0 + sr)*K + sc;

  auto stage = [&](int T){
    const int b = T % 3;
    const size_t ko = (size_t)T * 64;
    u16* dA = lds + b*24576 + wv*512;
    u16* dB = lds + b*24576 + 8192 + wv*512;
    gl_lds16(Asrc + ko,                    dA);
    gl_lds16(Asrc + (size_t)64*K + ko,     dA + 4096);
    #pragma unroll
    for(int j=0;j<4;j++)
      gl_lds16(Bsrc + (size_t)(j*64)*K + ko, dB + j*4096);
  };

  f4_t acc[4][4];
  #pragma unroll
  for(int i=0;i<4;i++)
    #pragma unroll
    for(int j=0;j<4;j++) acc[i][j] = f4_t{0.f,0.f,0.f,0.f};

  const int rA = wm*64 + lr;
  const int rB = wn*64 + lr;
  const int cxor = (lr & 7) << 4;

  auto compute = [&](int b){
    const char* La = (const char*)(lds + b*24576);
    const char* Lb = La + 16384;
    #pragma unroll
    for(int kk=0;kk<2;++kk){
      const int cb = (kk*64 + lg*16) ^ cxor;
      bf8_t af[4], bfr[4];
      #pragma unroll
      for(int m=0;m<4;m++) af[m]  = *(const bf8_t*)(La + (rA + m*16)*128 + cb);
      #pragma unroll
      for(int n=0;n<4;n++) bfr[n] = *(const bf8_t*)(Lb + (rB + n*16)*128 + cb);
      __builtin_amdgcn_s_setprio(1);
      #pragma unroll
      for(int m=0;m<4;m++)
        #pragma unroll
        for(int n=0;n<4;n++)
          acc[m][n] = MFMA_B16(af[m], bfr[n], acc[m][n]);
      __builtin_amdgcn_s_setprio(0);
    }
  };

  stage(0);
  stage(1);

  for(int T=0; T<NT-1; ++T){
    asm volatile("s_waitcnt vmcnt(6)" ::: "memory");
    __builtin_amdgcn_s_barrier();
    asm volatile("" ::: "memory");
    __builtin_amdgcn_sched_barrier(0);
    if(T+2 < NT) stage(T+2);
    compute(T % 3);
  }
  asm volatile("s_waitcnt vmcnt(0)" ::: "memory");
  __builtin_amdgcn_s_barrier();
  asm volatile("" ::: "memory");
  __builtin_amdgcn_sched_barrier(0);
  compute((NT-1) % 3);

  #pragma unroll
  for(int m=0;m<4;m++){
    #pragma unroll
    for(int n=0;n<4;n++){
      const int row0 = m0 + wm*64 + m*16 + lg*4;
      const int col  = n0 + wn*64 + n*16 + lr;
      #pragma unroll
      for(int r=0;r<4;r++){
        const size_t idx = (size_t)(row0+r)*N + col;
        float v = acc[m][n][r];
        if constexpr(EPI==E_BF16) ((u16*)Cp)[idx] = f2bf(v);
        else if constexpr(EPI==E_ADDF32) ((float*)Cp)[idx] = v + ((const float*)aux)[idx];
        else if constexpr(EPI==E_SILUMUL){
          float u = bf2f(((const u16*)aux)[idx]);
          ((u16*)Cp)[idx] = f2bf(u * v / (1.f + __expf(-v)));
        }
      }
    }
  }
}

// ---------- 256x256 8-phase GEMM (m201-style), for N>=2816 GEMMs ----------
// Same verified dataflow as round 9 (staging map, parity publish, vmcnt(6) at
// ph4/ph8, never draining mid-loop). FIXED phase microstructure per the m201
// template: {reads (LDB+LDA) -> STAGE -> s_barrier -> lgkmcnt(0) -> MFMA ->
// [vmcnt] -> s_barrier} — read latency hides under the mid-phase barrier.
template<int EPI>
__global__ __launch_bounds__(512, 2) void k_gemm10(
    const u16* __restrict__ A, const u16* __restrict__ Bt,
    void* __restrict__ Cp, const void* __restrict__ aux,
    int M, int N, int K)
{
  __shared__ __align__(16) char lds[131072];   // 128 KB
  const int t = threadIdx.x;
  const int wv = t >> 6, ln = t & 63, lr = ln & 15, lg = ln >> 4;
  const int wm = wv >> 2, wn = wv & 3;         // 2 M-waves x 4 N-waves
  int bm, bn; xcd_map(gridDim.x, gridDim.y, bm, bn);
  const int m0 = bm*256, n0 = bn*256;
  const int NT = K >> 6;                       // even for all users

  const int sl   = t & 7;
  const int pgl  = (t >> 3) & 7;
  const int unsw = 16*(sl ^ pgl);
  const int rloc = ((t >> 3) << 1) + (unsw >> 6);
  const int cole = (unsw & 63) >> 1;
  const u16* Asrc = A  + (size_t)(m0 + rloc)*K + cole;
  const u16* Bsrc = Bt + (size_t)(n0 + rloc)*K + cole;

  auto STAGE = [&](int tt, int mat, int kh){
    if(tt >= NT) return;
    const size_t ko = (size_t)tt*64 + kh*32;
    const u16* s = mat ? Bsrc : Asrc;
    char* d = lds + ((tt & 1) << 16) + (mat << 15) + (kh << 14) + (wv << 10);
    gl_lds16(s + ko,                  d);
    gl_lds16(s + (size_t)128*K + ko,  d + 8192);
  };

  f4_t acc[8][4];
  #pragma unroll
  for(int i=0;i<8;i++)
    #pragma unroll
    for(int j=0;j<4;j++) acc[i][j] = f4_t{0.f,0.f,0.f,0.f};

  bf8_t bfr[4];
  auto LDB = [&](int buf, int kk){
    #pragma unroll
    for(int n=0;n<4;n++){
      const int R = wn*64 + n*16 + lr;
      const int pg = R >> 1;
      const int off = (buf<<16) + 32768 + (kk<<14) + pg*128
                    + ((((R&1)<<6) | (lg<<4)) ^ ((pg&7)<<4));
      bfr[n] = *(const bf8_t*)(lds + off);
    }
  };
  auto LDA = [&](bf8_t* af, int buf, int kk, int mh){
    #pragma unroll
    for(int m=0;m<4;m++){
      const int R = wm*128 + (mh*4+m)*16 + lr;
      const int pg = R >> 1;
      const int off = (buf<<16) + (kk<<14) + pg*128
                    + ((((R&1)<<6) | (lg<<4)) ^ ((pg&7)<<4));
      af[m] = *(const bf8_t*)(lds + off);
    }
  };
  auto MFMAC = [&](bf8_t* af, int mh){
    asm volatile("s_waitcnt lgkmcnt(0)" ::: "memory");
    __builtin_amdgcn_sched_barrier(0);
    __builtin_amdgcn_s_setprio(1);
    #pragma unroll
    for(int m=0;m<4;m++)
      #pragma unroll
      for(int n=0;n<4;n++)
        acc[mh*4+m][n] = MFMA_B16(af[m], bfr[n], acc[mh*4+m][n]);
    __builtin_amdgcn_s_setprio(0);
  };

  #define GBAR do{ asm volatile("" ::: "memory"); __builtin_amdgcn_s_barrier(); \
                   asm volatile("" ::: "memory"); }while(0)

  // prologue: tile0 fully + tile1's B0,A0,B1; vmcnt(6) keeps tile1's 3 units.
  STAGE(0,1,0); STAGE(0,0,0); STAGE(0,1,1); STAGE(0,0,1);
  STAGE(1,1,0); STAGE(1,0,0); STAGE(1,1,1);
  asm volatile("s_waitcnt vmcnt(6)" ::: "memory");
  GBAR;

  const int NI = NT >> 1;
  for(int j=0; j<NI; ++j){
    const int t1 = 2*j+1;
    const bool last = (j == NI-1);
    bf8_t af[4];
    // ph1: buf0 (kk0, mh0); stage A-Kh1(t1) -> buf1
    LDB(0,0); LDA(af,0,0,0); STAGE(t1,0,1);
    GBAR; MFMAC(af,0); GBAR;
    // ph2: buf0 (kk0, mh1); stage B-Kh0(t1+1) -> buf0
    LDA(af,0,0,1); STAGE(t1+1,1,0);
    GBAR; MFMAC(af,1); GBAR;
    // ph3: buf0 (kk1, mh0); stage A-Kh0(t1+1) -> buf0
    LDB(0,1); LDA(af,0,1,0); STAGE(t1+1,0,0);
    GBAR; MFMAC(af,0); GBAR;
    // ph4: buf0 (kk1, mh1); stage B-Kh1(t1+1) -> buf0; vmcnt publish buf1
    LDA(af,0,1,1); STAGE(t1+1,1,1);
    GBAR; MFMAC(af,1);
    if(last) asm volatile("s_waitcnt vmcnt(0)" ::: "memory");
    else     asm volatile("s_waitcnt vmcnt(6)" ::: "memory");
    GBAR;
    // ph5: buf1 (kk0, mh0); stage A-Kh1(t1+1) -> buf0
    LDB(1,0); LDA(af,1,0,0); STAGE(t1+1,0,1);
    GBAR; MFMAC(af,0); GBAR;
    // ph6: buf1 (kk0, mh1); stage B-Kh0(t1+2) -> buf1
    LDA(af,1,0,1); STAGE(t1+2,1,0);
    GBAR; MFMAC(af,1); GBAR;
    // ph7: buf1 (kk1, mh0); stage A-Kh0(t1+2) -> buf1
    LDB(1,1); LDA(af,1,1,0); STAGE(t1+2,0,0);
    GBAR; MFMAC(af,0); GBAR;
    // ph8: buf1 (kk1, mh1); stage B-Kh1(t1+2) -> buf1; vmcnt publish buf0
    LDA(af,1,1,1); STAGE(t1+2,1,1);
    GBAR; MFMAC(af,1);
    if(!last){ asm volatile("s_waitcnt vmcnt(6)" ::: "memory"); }
    GBAR;
  }
  #undef GBAR

  #pragma unroll
  for(int m=0;m<8;m++){
    #pragma unroll
    for(int n=0;n<4;n++){
      const int row0 = m0 + wm*128 + m*16 + lg*4;
      const int col  = n0 + wn*64 + n*16 + lr;
      if constexpr(EPI==E_QKVG){
        char* wsb = (char*)Cp;
        if(n0 < 1024){                       // q,k -> qkb [8192][1024]
          u16* dst = (u16*)(wsb + OFF_QKB);
          #pragma unroll
          for(int r=0;r<4;r++) dst[(size_t)(row0+r)*1024 + col] = f2bf(acc[m][n][r]);
        } else if(n0 < 2048){                // v -> vtb transposed [1024][8192]
          u16* dst = (u16*)(wsb + OFF_VT);
          ushort4 u;
          u.x = f2bf(acc[m][n][0]); u.y = f2bf(acc[m][n][1]);
          u.z = f2bf(acc[m][n][2]); u.w = f2bf(acc[m][n][3]);
          *(ushort4*)(dst + (size_t)(col-1024)*TOKS + row0) = u;
        } else {                             // g -> gob [8192][1024]
          u16* dst = (u16*)(wsb + OFF_GO);
          #pragma unroll
          for(int r=0;r<4;r++) dst[(size_t)(row0+r)*1024 + (col-2048)] = f2bf(acc[m][n][r]);
        }
      } else {
        #pragma unroll
        for(int r=0;r<4;r++){
          const size_t idx = (size_t)(row0+r)*N + col;
          float v = acc[m][n][r];
          if constexpr(EPI==E_BF16) ((u16*)Cp)[idx] = f2bf(v);
          else if constexpr(EPI==E_ADDF32) ((float*)Cp)[idx] = v + ((const float*)aux)[idx];
          else if constexpr(EPI==E_SILUMUL){
            float u = bf2f(((const u16*)aux)[idx]);
            ((u16*)Cp)[idx] = f2bf(u * v / (1.f + __expf(-v)));
          }
        }
      }
    }
  }
}

// ---------- GLA phase A ----------
__global__ __launch_bounds__(256) void k_gla_a(
    const u16* __restrict__ QK,
    const u16* __restrict__ VT, const float* __restrict__ G,
    u16* __restrict__ QE, u16* __restrict__ OI,
    u16* __restrict__ CT, float* __restrict__ DEC)
{
  __shared__ __align__(16) u16 qe_s[64*128];
  __shared__ __align__(16) u16 ke_s[64*128];
  __shared__ __align__(16) u16 kd_s[128*64];
  __shared__ __align__(16) u16 a_s [64*64];
  __shared__ float ps_s[2][128];

  const int bid = blockIdx.x;
  const int nc = bid & 31, hh = (bid >> 5) & 3, bb = bid >> 7;
  const int bh = bb*4 + hh;
  const int tok0 = bb*2048 + nc*64;
  const int t = threadIdx.x;
  const size_t cbase = (size_t)(bh*32 + nc);

  {
    const int d = t & 127;
    const int half = t >> 7;
    const int col = hh*128 + d;
    const int i0 = half*32;
    float g[32];
    float psum = 0.f;
    #pragma unroll
    for(int i=0;i<32;i++){
      g[i] = G[(size_t)(tok0+i0+i)*512 + col];
      psum += g[i];
    }
    ps_s[half][d] = psum;
    __syncthreads();
    const float cum0  = half ? ps_s[0][d] : 0.f;
    const float blast = ps_s[0][d] + ps_s[1][d];
    if(half == 0) DEC[cbase*128 + d] = __expf(blast);
    float cum = cum0;
    #pragma unroll
    for(int i=0;i<32;i++){
      cum += g[i];
      const int tok = tok0 + i0 + i;
      float qv = bf2f(QK[(size_t)tok*1024 + col]);
      float kv = bf2f(QK[(size_t)tok*1024 + 512 + col]);
      float qe = qv * __expf(cum) * 0.08838834764831845f;
      float ke = kv * __expf(-cum);
      float kd = kv * __expf(blast - cum);
      *(u16*)((char*)qe_s + swz256(i0+i, d*2)) = f2bf(qe);
      *(u16*)((char*)ke_s + swz256(i0+i, d*2)) = f2bf(ke);
      *(u16*)((char*)kd_s + swz128(d, (i0+i)*2)) = f2bf(kd);
      QE[(cbase*64 + i0+i)*128 + d] = f2bf(qe);
    }
  }
  __syncthreads();

  const int wv = t >> 6, ln = t & 63, lr = ln & 15, lg = ln >> 4;

  bf8_t aq[4];
  #pragma unroll
  for(int ks=0;ks<4;ks++)
    aq[ks] = *(const bf8_t*)((const char*)qe_s + swz256(wv*16 + lr, ks*64 + lg*16));
  #pragma unroll
  for(int n=0;n<4;n++){
    f4_t accA = f4_t{0.f,0.f,0.f,0.f};
    #pragma unroll
    for(int ks=0;ks<4;ks++){
      bf8_t bk = *(const bf8_t*)((const char*)ke_s + swz256(n*16 + lr, ks*64 + lg*16));
      accA = MFMA_B16(aq[ks], bk, accA);
    }
    #pragma unroll
    for(int r=0;r<4;r++){
      int i = wv*16 + lg*4 + r;
      int s = n*16 + lr;
      float v = (s <= i) ? accA[r] : 0.f;
      *(u16*)((char*)a_s + swz128(i, s*2)) = f2bf(v);
    }
  }
  __syncthreads();

  bf8_t af[2], kf[2][2];
  #pragma unroll
  for(int ks=0;ks<2;ks++)
    af[ks] = *(const bf8_t*)((const char*)a_s + swz128(wv*16 + lr, ks*64 + lg*16));
  #pragma unroll
  for(int p=0;p<2;p++)
    #pragma unroll
    for(int ks=0;ks<2;ks++)
      kf[p][ks] = *(const bf8_t*)((const char*)kd_s + swz128((2*wv+p)*16 + lr, ks*64 + lg*16));

  #pragma unroll 4
  for(int ne=0; ne<16; ne++){
    bf8_t vf[2];
    #pragma unroll
    for(int ks=0;ks<2;ks++)
      vf[ks] = *(const bf8_t*)(VT + (size_t)(hh*256 + ne*16 + lr)*8192 + tok0 + ks*32 + lg*8);
    f4_t ao = f4_t{0.f,0.f,0.f,0.f};
    ao = MFMA_B16(af[0], vf[0], ao);
    ao = MFMA_B16(af[1], vf[1], ao);
    #pragma unroll
    for(int r=0;r<4;r++)
      OI[(cbase*64 + wv*16 + lg*4 + r)*256 + ne*16 + lr] = f2bf(ao[r]);
    f4_t c0 = f4_t{0.f,0.f,0.f,0.f}, c1 = f4_t{0.f,0.f,0.f,0.f};
    c0 = MFMA_B16(kf[0][0], vf[0], c0);
    c0 = MFMA_B16(kf[0][1], vf[1], c0);
    c1 = MFMA_B16(kf[1][0], vf[0], c1);
    c1 = MFMA_B16(kf[1][1], vf[1], c1);
    u16* dst = CT + (cbase*256 + ne*16 + lr)*128;
    ushort4 u0, u1;
    u0.x=f2bf(c0[0]); u0.y=f2bf(c0[1]); u0.z=f2bf(c0[2]); u0.w=f2bf(c0[3]);
    u1.x=f2bf(c1[0]); u1.y=f2bf(c1[1]); u1.z=f2bf(c1[2]); u1.w=f2bf(c1[3]);
    *(ushort4*)(dst + (2*wv+0)*16 + lg*4) = u0;
    *(ushort4*)(dst + (2*wv+1)*16 + lg*4) = u1;
  }
}

// ---------- GLA phase B ----------
__global__ __launch_bounds__(256) void k_scan(
    u16* __restrict__ CTST, const float* __restrict__ DEC)
{
  const int idx = blockIdx.x*256 + threadIdx.x;
  const int d = idx & 127;
  const int e = (idx >> 7) & 255;
  const int bh = idx >> 15;
  float s = 0.f;
  for(int n=0;n<32;n++){
    const size_t off = ((size_t)(bh*32 + n)*256 + e)*128 + d;
    float c = bf2f(CTST[off]);
    CTST[off] = f2bf(s);
    s = s * DEC[(bh*32+n)*128 + d] + c;
  }
}

// ---------- GLA phase C ----------
__global__ __launch_bounds__(256) void k_gla_c(
    const u16* __restrict__ QE, const u16* __restrict__ ST,
    const u16* __restrict__ OI, const u16* __restrict__ GO,
    const float* __restrict__ GW, u16* __restrict__ OG)
{
  const int bid = blockIdx.x;
  const int nc = bid & 31, hh = (bid >> 5) & 3, bb = bid >> 7;
  const int bh = bb*4 + hh;
  const int tok0 = bb*2048 + nc*64;
  const int t = threadIdx.x;
  const int wv = t >> 6, ln = t & 63, lr = ln & 15, lg = ln >> 4;
  const size_t cbase = (size_t)(bh*32 + nc);

  bf8_t qf[4];
  #pragma unroll
  for(int ks=0;ks<4;ks++)
    qf[ks] = *(const bf8_t*)(QE + (cbase*64 + wv*16 + lr)*128 + ks*32 + lg*8);

  f4_t acc[16];
  #pragma unroll
  for(int ne=0;ne<16;ne++){
    f4_t a = f4_t{0.f,0.f,0.f,0.f};
    #pragma unroll
    for(int ks=0;ks<4;ks++){
      bf8_t sf = *(const bf8_t*)(ST + (cbase*256 + ne*16 + lr)*128 + ks*32 + lg*8);
      a = MFMA_B16(qf[ks], sf, a);
    }
    acc[ne] = a;
  }

  float vals[16][4];
  float ss[4] = {0.f,0.f,0.f,0.f};
  #pragma unroll
  for(int ne=0;ne<16;ne++)
    #pragma unroll
    for(int r=0;r<4;r++){
      float v = acc[ne][r] + bf2f(OI[(cbase*64 + wv*16 + lg*4 + r)*256 + ne*16 + lr]);
      vals[ne][r] = v;
      ss[r] += v*v;
    }
  #pragma unroll
  for(int r=0;r<4;r++){
    ss[r] += __shfl_xor(ss[r], 1, 64);
    ss[r] += __shfl_xor(ss[r], 2, 64);
    ss[r] += __shfl_xor(ss[r], 4, 64);
    ss[r] += __shfl_xor(ss[r], 8, 64);
  }
  float rs[4];
  #pragma unroll
  for(int r=0;r<4;r++) rs[r] = rsqrtf(ss[r]*(1.f/256.f) + 1e-6f);

  #pragma unroll
  for(int ne=0;ne<16;ne++)
    #pragma unroll
    for(int r=0;r<4;r++){
      int i = wv*16 + lg*4 + r;
      int e = ne*16 + lr;
      const size_t idx = (size_t)(tok0+i)*1024 + hh*256 + e;
      float gg = bf2f(GO[idx]);
      float sg = gg / (1.f + __expf(-gg));
      OG[idx] = f2bf(vals[ne][r]*rs[r]*GW[e]*sg);
    }
}

extern "C" void kernel_launch(void* const* d_in, const int* in_sizes, int n_in,
                              void* d_out, int out_size, void* d_ws, size_t ws_size,
                              hipStream_t stream) {
  (void)in_sizes; (void)n_in; (void)out_size;
  if (ws_size < WS_NEED) return;

  const float* x       = (const float*)d_in[0];
  const float* attn_w  = (const float*)d_in[1];
  const float* Wq      = (const float*)d_in[2];
  const float* Wk      = (const float*)d_in[3];
  const float* Wv      = (const float*)d_in[4];
  const float* Wg      = (const float*)d_in[5];
  const float* Wgk1    = (const float*)d_in[6];
  const float* Wgk2    = (const float*)d_in[7];
  const float* bgk2    = (const float*)d_in[8];
  const float* gnw     = (const float*)d_in[9];
  const float* Wo      = (const float*)d_in[10];
  const float* mlpw    = (const float*)d_in[11];
  const float* Wgate   = (const float*)d_in[12];
  const float* Wup     = (const float*)d_in[13];
  const float* Wdown   = (const float*)d_in[14];
  char* ws = (char*)d_ws;

  u16*   wqt   = (u16*)(ws + OFF_WQT);
  u16*   wkt   = (u16*)(ws + OFF_WKT);
  u16*   wvt   = (u16*)(ws + OFF_WVT);
  u16*   wgt   = (u16*)(ws + OFF_WGT);
  u16*   wot   = (u16*)(ws + OFF_WOT);
  u16*   wgatet= (u16*)(ws + OFF_WGATET);
  u16*   wupt  = (u16*)(ws + OFF_WUPT);
  u16*   wdownt= (u16*)(ws + OFF_WDOWNT);
  u16*   qeb   = (u16*)(ws + OFF_QE);
  u16*   ctst  = (u16*)(ws + OFF_CTST);
  float* decb  = (float*)(ws + OFF_DEC);
  u16*   qkb   = (u16*)(ws + OFF_QKB);
  float* glogb = (float*)(ws + OFF_GLOG);
  u16*   vtb   = (u16*)(ws + OFF_VT);
  u16*   upb   = (u16*)(ws + OFF_UP);
  u16*   hb    = (u16*)(ws + OFF_H);
  u16*   oib   = (u16*)(ws + OFF_OI);
  u16*   n2b   = (u16*)(ws + OFF_N2);
  u16*   gob   = (u16*)(ws + OFF_GO);
  u16*   ogb   = (u16*)(ws + OFF_OG);
  float* x2b   = (float*)d_out;

  dim3 blk(256);
  dim3 blk8(512);

  TransAll ta;
  ta.src[0]=Wq;    ta.dst[0]=wqt;    ta.K[0]=HS;  ta.N[0]=DKTOT;
  ta.src[1]=Wk;    ta.dst[1]=wkt;    ta.K[1]=HS;  ta.N[1]=DKTOT;
  ta.src[2]=Wv;    ta.dst[2]=wvt;    ta.K[2]=HS;  ta.N[2]=DVTOT;
  ta.src[3]=Wg;    ta.dst[3]=wgt;    ta.K[3]=HS;  ta.N[3]=DVTOT;
  ta.src[4]=Wo;    ta.dst[4]=wot;    ta.K[4]=DVTOT; ta.N[4]=HS;
  ta.src[5]=Wgate; ta.dst[5]=wgatet; ta.K[5]=HS;  ta.N[5]=IM;
  ta.src[6]=Wup;   ta.dst[6]=wupt;   ta.K[6]=HS;  ta.N[6]=IM;
  ta.src[7]=Wdown; ta.dst[7]=wdownt; ta.K[7]=IM;  ta.N[7]=HS;
  {
    int cum = 0;
    for(int j=0;j<8;j++){ cum += (ta.N[j]>>6)*(ta.K[j]>>6); ta.end[j] = cum; }
  }
  k_transpose_all<<<3136, blk, 0, stream>>>(ta);

  // fused attention rmsnorm + gate logits, then one N=3072 GEMM for q|k|v|g
  k_rms_glog<<<TOKS, blk, 0, stream>>>(x, attn_w, hb, Wgk1, Wgk2, bgk2, glogb);
  k_gemm10<E_QKVG><<<dim3(12, 32), blk8, 0, stream>>>(hb, wqt, ws, nullptr, TOKS, 3072, HS);

  // GLA
  k_gla_a<<<512, blk, 0, stream>>>(qkb, vtb, glogb, qeb, oib, ctst, decb);
  k_scan <<<2048, blk, 0, stream>>>(ctst, decb);
  k_gla_c<<<512, blk, 0, stream>>>(qeb, ctst, oib, gob, gnw, ogb);

  // output projection + residual (x2 -> d_out as fp32)
  k_gemm8<E_ADDF32><<<dim3(4, 64), blk8, 0, stream>>>(ogb, wot, x2b, x, TOKS, HS, DVTOT);

  // MLP
  k_rmsnorm<<<TOKS, blk, 0, stream>>>(x2b, mlpw, n2b);
  k_gemm10<E_BF16>   <<<dim3(11, 32), blk8, 0, stream>>>(n2b, wupt,   upb, nullptr, TOKS, IM, HS);
  k_gemm10<E_SILUMUL><<<dim3(11, 32), blk8, 0, stream>>>(n2b, wgatet, upb, upb,     TOKS, IM, HS);
  k_gemm8<E_ADDF32>  <<<dim3(4, 64),  blk8, 0, stream>>>(upb, wdownt, x2b, x2b,     TOKS, HS, IM);
}

// Round 11
// 407.604 us; speedup vs baseline: 1.0993x; 1.0847x over previous
//
#include <hip/hip_runtime.h>

typedef unsigned short u16;
typedef __attribute__((ext_vector_type(8))) short bf8_t;   // 8 x bf16 (4 VGPRs)
typedef __attribute__((ext_vector_type(4))) float f4_t;

#define MFMA_B16(a,b,c) __builtin_amdgcn_mfma_f32_16x16x32_bf16(a,b,c,0,0,0)

// ---------- problem constants ----------
#define TOKS 8192   // B*T = 4*2048
#define HS   1024
#define DKTOT 512
#define DVTOT 1024
#define IM   2816

// ---------- workspace layout (bytes) ----------
constexpr size_t OFF_WQT    = 0;
constexpr size_t OFF_WKT    = OFF_WQT    + (size_t)DKTOT*HS*2;        // contiguous: q,k,v,g one slab
constexpr size_t OFF_WVT    = OFF_WKT    + (size_t)DKTOT*HS*2;
constexpr size_t OFF_WGT    = OFF_WVT    + (size_t)DVTOT*HS*2;
constexpr size_t OFF_WOT    = OFF_WGT    + (size_t)DVTOT*HS*2;
constexpr size_t OFF_WGATET = OFF_WOT    + (size_t)HS*DVTOT*2;
constexpr size_t OFF_WUPT   = OFF_WGATET + (size_t)IM*HS*2;
constexpr size_t OFF_WDOWNT = OFF_WUPT   + (size_t)IM*HS*2;
constexpr size_t OFF_QE     = OFF_WDOWNT + (size_t)HS*IM*2;           // bf16 8 MiB
constexpr size_t OFF_CTST   = OFF_QE     + (size_t)TOKS*DKTOT*2;      // bf16 32 MiB (CT -> S in place)
constexpr size_t OFF_DEC    = OFF_CTST   + (size_t)512*256*128*2;     // fp32 256 KiB
constexpr size_t OFF_R1     = OFF_DEC    + (size_t)512*128*4;
constexpr size_t OFF_QKB    = OFF_R1;                                 // bf16 [8192][1024] 16 MiB
constexpr size_t OFF_GLOG   = OFF_QKB    + (size_t)TOKS*1024*2;       // fp32 16 MiB
constexpr size_t OFF_VT     = OFF_GLOG   + (size_t)TOKS*DKTOT*4;      // bf16 16 MiB
constexpr size_t OFF_UP     = OFF_R1;                                 // bf16 44 MiB (aliases QK/GLOG/VT)
constexpr size_t OFF_R3     = OFF_R1 + 50331648;
constexpr size_t OFF_H      = OFF_R3;                                 // bf16 16 MiB
constexpr size_t OFF_OI     = OFF_R3;                                 // (after H dead)
constexpr size_t OFF_N2     = OFF_R3;                                 // (after OI dead)
constexpr size_t OFF_R4     = OFF_R3 + 16777216;
constexpr size_t OFF_GO     = OFF_R4;                                 // bf16 16 MiB
constexpr size_t OFF_OG     = OFF_R4;                                 // in-place with GO
constexpr size_t WS_NEED    = OFF_R4 + 16777216;

// ---------- helpers ----------
__device__ __forceinline__ u16 f2bf(float f){
  union{ float f; unsigned u; } x; x.f = f;
  unsigned r = x.u + 0x7FFFu + ((x.u >> 16) & 1u);   // RNE
  return (u16)(r >> 16);
}
__device__ __forceinline__ float bf2f(u16 u){
  union{ unsigned u; float f; } x; x.u = ((unsigned)u) << 16; return x.f;
}
__device__ __forceinline__ void gl_lds16(const void* g, void* l){
  __builtin_amdgcn_global_load_lds(
      (const __attribute__((address_space(1))) unsigned int*)g,
      (__attribute__((address_space(3))) unsigned int*)l, 16, 0, 0);
}
// XOR-swizzled LDS byte addressing (writer+reader both use these => bijective, safe)
__device__ __forceinline__ int swz128(int row, int cb){ return row*128 + (cb ^ ((row & 7)  << 4)); }
__device__ __forceinline__ int swz256(int row, int cb){ return row*256 + (cb ^ ((row & 15) << 4)); }

// XCD-aware + L2-aware block mapping. Requires nwg % 8 == 0 (all grids here comply).
__device__ __forceinline__ void xcd_map(int gx, int gy, int& bm, int& bn){
  const int i   = blockIdx.y*gx + blockIdx.x;
  const int cpx = (gx*gy) >> 3;
  const int j   = (i & 7)*cpx + (i >> 3);
  const int k   = j / (gx*8);
  const int jl  = j - k*(gx*8);
  bn = jl >> 3;
  bm = k*8 + (jl & 7);
}

// ---------- batched weight transpose fp32 (K x N) -> bf16 (N x K) ----------
struct TransAll {
  const float* src[8];
  u16* dst[8];
  int K[8];
  int N[8];
  int end[8];   // cumulative tile counts
};

__global__ __launch_bounds__(256) void k_transpose_all(TransAll ta)
{
  __shared__ float tile[64][65];
  const int flat = blockIdx.x;
  int seg = 0, start = 0;
  #pragma unroll
  for(int j=0;j<8;j++){
    if(flat >= ta.end[j]){ seg = j+1; start = ta.end[j]; }
  }
  const float* W = ta.src[seg];
  u16* Wt = ta.dst[seg];
  const int K = ta.K[seg], N = ta.N[seg];
  const int local = flat - start;
  const int tilesX = N >> 6;
  const int n0 = (local % tilesX)*64, k0 = (local / tilesX)*64;
  const int tx = threadIdx.x & 63, tg = threadIdx.x >> 6;
  #pragma unroll
  for(int i=0;i<16;i++){
    int kr = tg*16 + i;
    tile[kr][tx] = W[(size_t)(k0+kr)*N + n0 + tx];
  }
  __syncthreads();
  #pragma unroll
  for(int i=0;i<16;i++){
    int nr = tg*16 + i;
    Wt[(size_t)(n0+nr)*K + k0 + tx] = f2bf(tile[tx][nr]);
  }
}

// ---------- RMSNorm: fp32 row -> bf16 row (MLP norm) ----------
__global__ __launch_bounds__(256) void k_rmsnorm(
    const float* __restrict__ X, const float* __restrict__ W, u16* __restrict__ H)
{
  __shared__ float red[4];
  const size_t row = blockIdx.x;
  const int t = threadIdx.x;
  const float4 v = ((const float4*)(X + row*1024))[t];
  float ss = v.x*v.x + v.y*v.y + v.z*v.z + v.w*v.w;
  #pragma unroll
  for(int m=32;m>=1;m>>=1) ss += __shfl_xor(ss, m, 64);
  if((t & 63) == 0) red[t >> 6] = ss;
  __syncthreads();
  ss = red[0] + red[1] + red[2] + red[3];
  const float rs = rsqrtf(ss*(1.f/1024.f) + 1e-6f);
  const float4 w = ((const float4*)W)[t];
  ushort4 o;
  o.x = f2bf(v.x*rs*w.x);
  o.y = f2bf(v.y*rs*w.y);
  o.z = f2bf(v.z*rs*w.z);
  o.w = f2bf(v.w*rs*w.w);
  ((ushort4*)H)[row*256 + t] = o;
}

// ---------- fused attention RMSNorm + low-rank gate logits ----------
__global__ __launch_bounds__(256) void k_rms_glog(
    const float* __restrict__ X, const float* __restrict__ W, u16* __restrict__ H,
    const float* __restrict__ W1, const float* __restrict__ W2,
    const float* __restrict__ bias, float* __restrict__ G)
{
  __shared__ float hs[1024];
  __shared__ float red2[16][17];
  __shared__ float rr[16];
  __shared__ float red[4];
  const size_t row = blockIdx.x;
  const int t = threadIdx.x;
  const float4 v = ((const float4*)(X + row*1024))[t];
  float ss = v.x*v.x + v.y*v.y + v.z*v.z + v.w*v.w;
  #pragma unroll
  for(int m=32;m>=1;m>>=1) ss += __shfl_xor(ss, m, 64);
  if((t & 63) == 0) red[t >> 6] = ss;
  __syncthreads();
  ss = red[0] + red[1] + red[2] + red[3];
  const float rs = rsqrtf(ss*(1.f/1024.f) + 1e-6f);
  const float4 w = ((const float4*)W)[t];
  const float h0 = v.x*rs*w.x, h1 = v.y*rs*w.y, h2 = v.z*rs*w.z, h3 = v.w*rs*w.w;
  ushort4 o; o.x = f2bf(h0); o.y = f2bf(h1); o.z = f2bf(h2); o.w = f2bf(h3);
  ((ushort4*)H)[row*256 + t] = o;
  hs[t*4+0] = h0; hs[t*4+1] = h1; hs[t*4+2] = h2; hs[t*4+3] = h3;
  __syncthreads();

  const int r = t & 15, c = t >> 4;
  float acc = 0.f;
  #pragma unroll
  for(int j=0;j<64;j++){
    int k = c*64 + ((j + c) & 63);
    acc += hs[k] * W1[(size_t)k*16 + r];
  }
  red2[c][r] = acc;
  __syncthreads();
  if(t < 16){
    float s2 = 0.f;
    #pragma unroll
    for(int cc=0;cc<16;cc++) s2 += red2[cc][t];
    rr[t] = s2;
  }
  __syncthreads();
  #pragma unroll
  for(int dd=0;dd<2;dd++){
    int dcol = t + dd*256;
    float z = bias[dcol];
    #pragma unroll
    for(int j=0;j<16;j++) z += rr[j]*W2[j*512 + dcol];
    float ls = fminf(z, 0.f) - log1pf(__expf(-fabsf(z)));
    G[row*512 + dcol] = ls * 0.0625f;
  }
}

enum { E_BF16=1, E_ADDF32=2, E_QKVG=5 };

// ---------- pipelined GEMM: C[MxN] = A[MxK](bf16) * Bt[NxK](bf16)^T ----------
// BM=128, BN=256, BK=64, 512 threads (8 waves, 2Mx4N), 3-deep LDS pipeline,
// counted vmcnt(6) (never drains in main loop), raw s_barrier, T2 swizzle, T5 setprio.
template<int EPI>
__global__ __launch_bounds__(512, 2) void k_gemm8(
    const u16* __restrict__ A, const u16* __restrict__ Bt,
    void* __restrict__ Cp, const void* __restrict__ aux,
    int M, int N, int K)
{
  // 3 buffers x (A: 128x64 = 16KB, B: 256x64 = 32KB) = 147456 B
  __shared__ __align__(16) u16 lds[3*24576];
  const int t = threadIdx.x;
  const int wv = t >> 6, ln = t & 63, lr = ln & 15, lg = ln >> 4;
  const int wm = wv >> 2, wn = wv & 3;
  int bm, bn; xcd_map(gridDim.x, gridDim.y, bm, bn);
  const int m0 = bm*128, n0 = bn*256;
  const int NT = K >> 6;

  const int sr = t >> 3;                               // row within 64-row issue
  const int sc = ((t & 7)*16 ^ ((sr & 7) << 4)) >> 1;  // source col element (pre-swizzled)
  const u16* Asrc = A  + (size_t)(m0 + sr)*K + sc;
  const u16* Bsrc = Bt + (size_t)(n0 + sr)*K + sc;

  auto stage = [&](int T){
    const int b = T % 3;
    const size_t ko = (size_t)T * 64;
    u16* dA = lds + b*24576 + wv*512;
    u16* dB = lds + b*24576 + 8192 + wv*512;
    gl_lds16(Asrc + ko,                    dA);
    gl_lds16(Asrc + (size_t)64*K + ko,     dA + 4096);
    #pragma unroll
    for(int j=0;j<4;j++)
      gl_lds16(Bsrc + (size_t)(j*64)*K + ko, dB + j*4096);
  };

  f4_t acc[4][4];
  #pragma unroll
  for(int i=0;i<4;i++)
    #pragma unroll
    for(int j=0;j<4;j++) acc[i][j] = f4_t{0.f,0.f,0.f,0.f};

  const int rA = wm*64 + lr;
  const int rB = wn*64 + lr;
  const int cxor = (lr & 7) << 4;

  auto compute = [&](int b){
    const char* La = (const char*)(lds + b*24576);
    const char* Lb = La + 16384;
    #pragma unroll
    for(int kk=0;kk<2;++kk){
      const int cb = (kk*64 + lg*16) ^ cxor;
      bf8_t af[4], bfr[4];
      #pragma unroll
      for(int m=0;m<4;m++) af[m]  = *(const bf8_t*)(La + (rA + m*16)*128 + cb);
      #pragma unroll
      for(int n=0;n<4;n++) bfr[n] = *(const bf8_t*)(Lb + (rB + n*16)*128 + cb);
      __builtin_amdgcn_s_setprio(1);
      #pragma unroll
      for(int m=0;m<4;m++)
        #pragma unroll
        for(int n=0;n<4;n++)
          acc[m][n] = MFMA_B16(af[m], bfr[n], acc[m][n]);
      __builtin_amdgcn_s_setprio(0);
    }
  };

  stage(0);
  stage(1);

  for(int T=0; T<NT-1; ++T){
    asm volatile("s_waitcnt vmcnt(6)" ::: "memory");
    __builtin_amdgcn_s_barrier();
    asm volatile("" ::: "memory");
    __builtin_amdgcn_sched_barrier(0);
    if(T+2 < NT) stage(T+2);
    compute(T % 3);
  }
  asm volatile("s_waitcnt vmcnt(0)" ::: "memory");
  __builtin_amdgcn_s_barrier();
  asm volatile("" ::: "memory");
  __builtin_amdgcn_sched_barrier(0);
  compute((NT-1) % 3);

  #pragma unroll
  for(int m=0;m<4;m++){
    #pragma unroll
    for(int n=0;n<4;n++){
      const int row0 = m0 + wm*64 + m*16 + lg*4;
      const int col  = n0 + wn*64 + n*16 + lr;
      if constexpr(EPI==E_QKVG){
        char* wsb = (char*)Cp;
        if(n0 < 1024){                       // q,k -> qkb [8192][1024]
          u16* dst = (u16*)(wsb + OFF_QKB);
          #pragma unroll
          for(int r=0;r<4;r++) dst[(size_t)(row0+r)*1024 + col] = f2bf(acc[m][n][r]);
        } else if(n0 < 2048){                // v -> vtb transposed [1024][8192]
          u16* dst = (u16*)(wsb + OFF_VT);
          ushort4 u;
          u.x = f2bf(acc[m][n][0]); u.y = f2bf(acc[m][n][1]);
          u.z = f2bf(acc[m][n][2]); u.w = f2bf(acc[m][n][3]);
          *(ushort4*)(dst + (size_t)(col-1024)*TOKS + row0) = u;
        } else {                             // g -> gob [8192][1024]
          u16* dst = (u16*)(wsb + OFF_GO);
          #pragma unroll
          for(int r=0;r<4;r++) dst[(size_t)(row0+r)*1024 + (col-2048)] = f2bf(acc[m][n][r]);
        }
      } else {
        #pragma unroll
        for(int r=0;r<4;r++){
          const size_t idx = (size_t)(row0+r)*N + col;
          float v = acc[m][n][r];
          if constexpr(EPI==E_BF16) ((u16*)Cp)[idx] = f2bf(v);
          else if constexpr(EPI==E_ADDF32) ((float*)Cp)[idx] = v + ((const float*)aux)[idx];
        }
      }
    }
  }
}

// ---------- fused up+gate GEMM, k_gemm8 pipeline clone ----------
// BM=128, BN=128 (dual outputs), BK=64, 512 threads (8 waves, 2Mx4N; per-wave
// 64x32 of EACH matrix). 3 buffers x (A 16KB + Bu 16KB + Bg 16KB) = 147456 B.
// Staging = 6 gl_lds16/tile, vmcnt(6) discipline identical to k_gemm8.
// out = up * silu(gate), bf16.
__global__ __launch_bounds__(512, 2) void k_gemm8_ug(
    const u16* __restrict__ A, const u16* __restrict__ Bu,
    const u16* __restrict__ Bg, u16* __restrict__ Cp,
    int M, int N, int K)
{
  __shared__ __align__(16) u16 lds[3*24576];
  const int t = threadIdx.x;
  const int wv = t >> 6, ln = t & 63, lr = ln & 15, lg = ln >> 4;
  const int wm = wv >> 2, wn = wv & 3;
  int bm, bn; xcd_map(gridDim.x, gridDim.y, bm, bn);
  const int m0 = bm*128, n0 = bn*128;
  const int NT = K >> 6;

  const int sr = t >> 3;
  const int sc = ((t & 7)*16 ^ ((sr & 7) << 4)) >> 1;
  const u16* Asrc  = A  + (size_t)(m0 + sr)*K + sc;
  const u16* Busrc = Bu + (size_t)(n0 + sr)*K + sc;
  const u16* Bgsrc = Bg + (size_t)(n0 + sr)*K + sc;

  auto stage = [&](int T){
    const int b = T % 3;
    const size_t ko = (size_t)T * 64;
    u16* dA  = lds + b*24576 +         wv*512;
    u16* dBu = lds + b*24576 + 8192  + wv*512;
    u16* dBg = lds + b*24576 + 16384 + wv*512;
    gl_lds16(Asrc  + ko,                 dA);
    gl_lds16(Asrc  + (size_t)64*K + ko,  dA  + 4096);
    gl_lds16(Busrc + ko,                 dBu);
    gl_lds16(Busrc + (size_t)64*K + ko,  dBu + 4096);
    gl_lds16(Bgsrc + ko,                 dBg);
    gl_lds16(Bgsrc + (size_t)64*K + ko,  dBg + 4096);
  };

  f4_t accU[4][2], accG[4][2];
  #pragma unroll
  for(int i=0;i<4;i++)
    #pragma unroll
    for(int j=0;j<2;j++){ accU[i][j] = f4_t{0.f,0.f,0.f,0.f}; accG[i][j] = f4_t{0.f,0.f,0.f,0.f}; }

  const int rA = wm*64 + lr;
  const int rB = wn*32 + lr;
  const int cxor = (lr & 7) << 4;

  auto compute = [&](int b){
    const char* La  = (const char*)(lds + b*24576);
    const char* Lbu = La + 16384;
    const char* Lbg = La + 32768;
    #pragma unroll
    for(int kk=0;kk<2;++kk){
      const int cb = (kk*64 + lg*16) ^ cxor;
      bf8_t af[4], bu[2], bg[2];
      #pragma unroll
      for(int m=0;m<4;m++) af[m] = *(const bf8_t*)(La  + (rA + m*16)*128 + cb);
      #pragma unroll
      for(int n=0;n<2;n++){
        bu[n] = *(const bf8_t*)(Lbu + (rB + n*16)*128 + cb);
        bg[n] = *(const bf8_t*)(Lbg + (rB + n*16)*128 + cb);
      }
      __builtin_amdgcn_s_setprio(1);
      #pragma unroll
      for(int m=0;m<4;m++)
        #pragma unroll
        for(int n=0;n<2;n++){
          accU[m][n] = MFMA_B16(af[m], bu[n], accU[m][n]);
          accG[m][n] = MFMA_B16(af[m], bg[n], accG[m][n]);
        }
      __builtin_amdgcn_s_setprio(0);
    }
  };

  stage(0);
  stage(1);

  for(int T=0; T<NT-1; ++T){
    asm volatile("s_waitcnt vmcnt(6)" ::: "memory");
    __builtin_amdgcn_s_barrier();
    asm volatile("" ::: "memory");
    __builtin_amdgcn_sched_barrier(0);
    if(T+2 < NT) stage(T+2);
    compute(T % 3);
  }
  asm volatile("s_waitcnt vmcnt(0)" ::: "memory");
  __builtin_amdgcn_s_barrier();
  asm volatile("" ::: "memory");
  __builtin_amdgcn_sched_barrier(0);
  compute((NT-1) % 3);

  #pragma unroll
  for(int m=0;m<4;m++){
    #pragma unroll
    for(int n=0;n<2;n++){
      const int row0 = m0 + wm*64 + m*16 + lg*4;
      const int col  = n0 + wn*32 + n*16 + lr;
      #pragma unroll
      for(int r=0;r<4;r++){
        const size_t idx = (size_t)(row0+r)*N + col;
        float uv = accU[m][n][r];
        float gv = accG[m][n][r];
        Cp[idx] = f2bf(uv * gv / (1.f + __expf(-gv)));
      }
    }
  }
}

// ---------- GLA phase A ----------
__global__ __launch_bounds__(256) void k_gla_a(
    const u16* __restrict__ QK,
    const u16* __restrict__ VT, const float* __restrict__ G,
    u16* __restrict__ QE, u16* __restrict__ OI,
    u16* __restrict__ CT, float* __restrict__ DEC)
{
  __shared__ __align__(16) u16 qe_s[64*128];
  __shared__ __align__(16) u16 ke_s[64*128];
  __shared__ __align__(16) u16 kd_s[128*64];
  __shared__ __align__(16) u16 a_s [64*64];
  __shared__ float ps_s[2][128];

  const int bid = blockIdx.x;
  const int nc = bid & 31, hh = (bid >> 5) & 3, bb = bid >> 7;
  const int bh = bb*4 + hh;
  const int tok0 = bb*2048 + nc*64;
  const int t = threadIdx.x;
  const size_t cbase = (size_t)(bh*32 + nc);

  {
    const int d = t & 127;
    const int half = t >> 7;
    const int col = hh*128 + d;
    const int i0 = half*32;
    float g[32];
    float psum = 0.f;
    #pragma unroll
    for(int i=0;i<32;i++){
      g[i] = G[(size_t)(tok0+i0+i)*512 + col];
      psum += g[i];
    }
    ps_s[half][d] = psum;
    __syncthreads();
    const float cum0  = half ? ps_s[0][d] : 0.f;
    const float blast = ps_s[0][d] + ps_s[1][d];
    if(half == 0) DEC[cbase*128 + d] = __expf(blast);
    float cum = cum0;
    #pragma unroll
    for(int i=0;i<32;i++){
      cum += g[i];
      const int tok = tok0 + i0 + i;
      float qv = bf2f(QK[(size_t)tok*1024 + col]);
      float kv = bf2f(QK[(size_t)tok*1024 + 512 + col]);
      float qe = qv * __expf(cum) * 0.08838834764831845f;
      float ke = kv * __expf(-cum);
      float kd = kv * __expf(blast - cum);
      *(u16*)((char*)qe_s + swz256(i0+i, d*2)) = f2bf(qe);
      *(u16*)((char*)ke_s + swz256(i0+i, d*2)) = f2bf(ke);
      *(u16*)((char*)kd_s + swz128(d, (i0+i)*2)) = f2bf(kd);
      QE[(cbase*64 + i0+i)*128 + d] = f2bf(qe);
    }
  }
  __syncthreads();

  const int wv = t >> 6, ln = t & 63, lr = ln & 15, lg = ln >> 4;

  bf8_t aq[4];
  #pragma unroll
  for(int ks=0;ks<4;ks++)
    aq[ks] = *(const bf8_t*)((const char*)qe_s + swz256(wv*16 + lr, ks*64 + lg*16));
  #pragma unroll
  for(int n=0;n<4;n++){
    f4_t accA = f4_t{0.f,0.f,0.f,0.f};
    #pragma unroll
    for(int ks=0;ks<4;ks++){
      bf8_t bk = *(const bf8_t*)((const char*)ke_s + swz256(n*16 + lr, ks*64 + lg*16));
      accA = MFMA_B16(aq[ks], bk, accA);
    }
    #pragma unroll
    for(int r=0;r<4;r++){
      int i = wv*16 + lg*4 + r;
      int s = n*16 + lr;
      float v = (s <= i) ? accA[r] : 0.f;
      *(u16*)((char*)a_s + swz128(i, s*2)) = f2bf(v);
    }
  }
  __syncthreads();

  bf8_t af[2], kf[2][2];
  #pragma unroll
  for(int ks=0;ks<2;ks++)
    af[ks] = *(const bf8_t*)((const char*)a_s + swz128(wv*16 + lr, ks*64 + lg*16));
  #pragma unroll
  for(int p=0;p<2;p++)
    #pragma unroll
    for(int ks=0;ks<2;ks++)
      kf[p][ks] = *(const bf8_t*)((const char*)kd_s + swz128((2*wv+p)*16 + lr, ks*64 + lg*16));

  #pragma unroll 4
  for(int ne=0; ne<16; ne++){
    bf8_t vf[2];
    #pragma unroll
    for(int ks=0;ks<2;ks++)
      vf[ks] = *(const bf8_t*)(VT + (size_t)(hh*256 + ne*16 + lr)*8192 + tok0 + ks*32 + lg*8);
    f4_t ao = f4_t{0.f,0.f,0.f,0.f};
    ao = MFMA_B16(af[0], vf[0], ao);
    ao = MFMA_B16(af[1], vf[1], ao);
    #pragma unroll
    for(int r=0;r<4;r++)
      OI[(cbase*64 + wv*16 + lg*4 + r)*256 + ne*16 + lr] = f2bf(ao[r]);
    f4_t c0 = f4_t{0.f,0.f,0.f,0.f}, c1 = f4_t{0.f,0.f,0.f,0.f};
    c0 = MFMA_B16(kf[0][0], vf[0], c0);
    c0 = MFMA_B16(kf[0][1], vf[1], c0);
    c1 = MFMA_B16(kf[1][0], vf[0], c1);
    c1 = MFMA_B16(kf[1][1], vf[1], c1);
    u16* dst = CT + (cbase*256 + ne*16 + lr)*128;
    ushort4 u0, u1;
    u0.x=f2bf(c0[0]); u0.y=f2bf(c0[1]); u0.z=f2bf(c0[2]); u0.w=f2bf(c0[3]);
    u1.x=f2bf(c1[0]); u1.y=f2bf(c1[1]); u1.z=f2bf(c1[2]); u1.w=f2bf(c1[3]);
    *(ushort4*)(dst + (2*wv+0)*16 + lg*4) = u0;
    *(ushort4*)(dst + (2*wv+1)*16 + lg*4) = u1;
  }
}

// ---------- GLA phase B ----------
__global__ __launch_bounds__(256) void k_scan(
    u16* __restrict__ CTST, const float* __restrict__ DEC)
{
  const int idx = blockIdx.x*256 + threadIdx.x;
  const int d = idx & 127;
  const int e = (idx >> 7) & 255;
  const int bh = idx >> 15;
  float s = 0.f;
  for(int n=0;n<32;n++){
    const size_t off = ((size_t)(bh*32 + n)*256 + e)*128 + d;
    float c = bf2f(CTST[off]);
    CTST[off] = f2bf(s);
    s = s * DEC[(bh*32+n)*128 + d] + c;
  }
}

// ---------- GLA phase C ----------
__global__ __launch_bounds__(256) void k_gla_c(
    const u16* __restrict__ QE, const u16* __restrict__ ST,
    const u16* __restrict__ OI, const u16* __restrict__ GO,
    const float* __restrict__ GW, u16* __restrict__ OG)
{
  const int bid = blockIdx.x;
  const int nc = bid & 31, hh = (bid >> 5) & 3, bb = bid >> 7;
  const int bh = bb*4 + hh;
  const int tok0 = bb*2048 + nc*64;
  const int t = threadIdx.x;
  const int wv = t >> 6, ln = t & 63, lr = ln & 15, lg = ln >> 4;
  const size_t cbase = (size_t)(bh*32 + nc);

  bf8_t qf[4];
  #pragma unroll
  for(int ks=0;ks<4;ks++)
    qf[ks] = *(const bf8_t*)(QE + (cbase*64 + wv*16 + lr)*128 + ks*32 + lg*8);

  f4_t acc[16];
  #pragma unroll
  for(int ne=0;ne<16;ne++){
    f4_t a = f4_t{0.f,0.f,0.f,0.f};
    #pragma unroll
    for(int ks=0;ks<4;ks++){
      bf8_t sf = *(const bf8_t*)(ST + (cbase*256 + ne*16 + lr)*128 + ks*32 + lg*8);
      a = MFMA_B16(qf[ks], sf, a);
    }
    acc[ne] = a;
  }

  float vals[16][4];
  float ss[4] = {0.f,0.f,0.f,0.f};
  #pragma unroll
  for(int ne=0;ne<16;ne++)
    #pragma unroll
    for(int r=0;r<4;r++){
      float v = acc[ne][r] + bf2f(OI[(cbase*64 + wv*16 + lg*4 + r)*256 + ne*16 + lr]);
      vals[ne][r] = v;
      ss[r] += v*v;
    }
  #pragma unroll
  for(int r=0;r<4;r++){
    ss[r] += __shfl_xor(ss[r], 1, 64);
    ss[r] += __shfl_xor(ss[r], 2, 64);
    ss[r] += __shfl_xor(ss[r], 4, 64);
    ss[r] += __shfl_xor(ss[r], 8, 64);
  }
  float rs[4];
  #pragma unroll
  for(int r=0;r<4;r++) rs[r] = rsqrtf(ss[r]*(1.f/256.f) + 1e-6f);

  #pragma unroll
  for(int ne=0;ne<16;ne++)
    #pragma unroll
    for(int r=0;r<4;r++){
      int i = wv*16 + lg*4 + r;
      int e = ne*16 + lr;
      const size_t idx = (size_t)(tok0+i)*1024 + hh*256 + e;
      float gg = bf2f(GO[idx]);
      float sg = gg / (1.f + __expf(-gg));
      OG[idx] = f2bf(vals[ne][r]*rs[r]*GW[e]*sg);
    }
}

extern "C" void kernel_launch(void* const* d_in, const int* in_sizes, int n_in,
                              void* d_out, int out_size, void* d_ws, size_t ws_size,
                              hipStream_t stream) {
  (void)in_sizes; (void)n_in; (void)out_size;
  if (ws_size < WS_NEED) return;

  const float* x       = (const float*)d_in[0];
  const float* attn_w  = (const float*)d_in[1];
  const float* Wq      = (const float*)d_in[2];
  const float* Wk      = (const float*)d_in[3];
  const float* Wv      = (const float*)d_in[4];
  const float* Wg      = (const float*)d_in[5];
  const float* Wgk1    = (const float*)d_in[6];
  const float* Wgk2    = (const float*)d_in[7];
  const float* bgk2    = (const float*)d_in[8];
  const float* gnw     = (const float*)d_in[9];
  const float* Wo      = (const float*)d_in[10];
  const float* mlpw    = (const float*)d_in[11];
  const float* Wgate   = (const float*)d_in[12];
  const float* Wup     = (const float*)d_in[13];
  const float* Wdown   = (const float*)d_in[14];
  char* ws = (char*)d_ws;

  u16*   wqt   = (u16*)(ws + OFF_WQT);
  u16*   wkt   = (u16*)(ws + OFF_WKT);
  u16*   wvt   = (u16*)(ws + OFF_WVT);
  u16*   wgt   = (u16*)(ws + OFF_WGT);
  u16*   wot   = (u16*)(ws + OFF_WOT);
  u16*   wgatet= (u16*)(ws + OFF_WGATET);
  u16*   wupt  = (u16*)(ws + OFF_WUPT);
  u16*   wdownt= (u16*)(ws + OFF_WDOWNT);
  u16*   qeb   = (u16*)(ws + OFF_QE);
  u16*   ctst  = (u16*)(ws + OFF_CTST);
  float* decb  = (float*)(ws + OFF_DEC);
  u16*   qkb   = (u16*)(ws + OFF_QKB);
  float* glogb = (float*)(ws + OFF_GLOG);
  u16*   vtb   = (u16*)(ws + OFF_VT);
  u16*   upb   = (u16*)(ws + OFF_UP);
  u16*   hb    = (u16*)(ws + OFF_H);
  u16*   oib   = (u16*)(ws + OFF_OI);
  u16*   n2b   = (u16*)(ws + OFF_N2);
  u16*   gob   = (u16*)(ws + OFF_GO);
  u16*   ogb   = (u16*)(ws + OFF_OG);
  float* x2b   = (float*)d_out;

  dim3 blk(256);
  dim3 blk8(512);

  TransAll ta;
  ta.src[0]=Wq;    ta.dst[0]=wqt;    ta.K[0]=HS;  ta.N[0]=DKTOT;
  ta.src[1]=Wk;    ta.dst[1]=wkt;    ta.K[1]=HS;  ta.N[1]=DKTOT;
  ta.src[2]=Wv;    ta.dst[2]=wvt;    ta.K[2]=HS;  ta.N[2]=DVTOT;
  ta.src[3]=Wg;    ta.dst[3]=wgt;    ta.K[3]=HS;  ta.N[3]=DVTOT;
  ta.src[4]=Wo;    ta.dst[4]=wot;    ta.K[4]=DVTOT; ta.N[4]=HS;
  ta.src[5]=Wgate; ta.dst[5]=wgatet; ta.K[5]=HS;  ta.N[5]=IM;
  ta.src[6]=Wup;   ta.dst[6]=wupt;   ta.K[6]=HS;  ta.N[6]=IM;
  ta.src[7]=Wdown; ta.dst[7]=wdownt; ta.K[7]=IM;  ta.N[7]=HS;
  {
    int cum = 0;
    for(int j=0;j<8;j++){ cum += (ta.N[j]>>6)*(ta.K[j]>>6); ta.end[j] = cum; }
  }
  k_transpose_all<<<3136, blk, 0, stream>>>(ta);

  // fused attention rmsnorm + gate logits, then one N=3072 GEMM for q|k|v|g
  k_rms_glog<<<TOKS, blk, 0, stream>>>(x, attn_w, hb, Wgk1, Wgk2, bgk2, glogb);
  k_gemm8<E_QKVG><<<dim3(12, 64), blk8, 0, stream>>>(hb, wqt, ws, nullptr, TOKS, 3072, HS);

  // GLA
  k_gla_a<<<512, blk, 0, stream>>>(qkb, vtb, glogb, qeb, oib, ctst, decb);
  k_scan <<<2048, blk, 0, stream>>>(ctst, decb);
  k_gla_c<<<512, blk, 0, stream>>>(qeb, ctst, oib, gob, gnw, ogb);

  // output projection + residual (x2 -> d_out as fp32)
  k_gemm8<E_ADDF32><<<dim3(4, 64), blk8, 0, stream>>>(ogb, wot, x2b, x, TOKS, HS, DVTOT);

  // MLP: fused up+gate (silu applied in epilogue), then down + residual
  k_rmsnorm<<<TOKS, blk, 0, stream>>>(x2b, mlpw, n2b);
  k_gemm8_ug<<<dim3(22, 64), blk8, 0, stream>>>(n2b, wupt, wgatet, upb, TOKS, IM, HS);
  k_gemm8<E_ADDF32><<<dim3(4, 64), blk8, 0, stream>>>(upb, wdownt, x2b, x2b, TOKS, HS, IM);
}